// Round 1
// baseline (605.939 us; speedup 1.0000x reference)
//
#include <hip/hip_runtime.h>
#include <math.h>

// Problem constants (B=2, T=2048, D=1024, H=16, HD=64, C=16)
#define B_    2
#define T_    2048
#define D_    1024
#define H_    16
#define HD_   64
#define C_    16
#define NQK_  256          // H_*C_
#define SCALE_ 0.125f      // HEAD_DIM^-0.5
#define L_    128          // time-chunk length
#define NC_   16           // T_/L_

// ---------------------------------------------------------------------------
// Fold fc_code into the q/k slices of w_qkv:
//   Wqc[h*16+c, e] = scale * sum_d w_qkv[h*64+d, e]        * code[h,c,d]
//   Wkc[h*16+c, e] = scale * sum_d w_qkv[1024+h*64+d, e]   * code[h,c,d]
__global__ __launch_bounds__(256)
void fold_code_kernel(const float* __restrict__ w_qkv, const float* __restrict__ code,
                      float* __restrict__ Wqc, float* __restrict__ Wkc) {
    const int bid = blockIdx.x;      // 0..511
    const int isK = bid >> 8;        // 0 => q, 1 => k
    const int row = bid & 255;       // h*16+c
    const int h = row >> 4;
    __shared__ float cs[HD_];
    if (threadIdx.x < HD_) cs[threadIdx.x] = code[row * HD_ + threadIdx.x];
    __syncthreads();
    const float* wbase = w_qkv + (size_t)(isK * D_ + h * HD_) * D_;
    float* outp = (isK ? Wkc : Wqc) + (size_t)row * D_;
    for (int e = threadIdx.x; e < D_; e += 256) {
        float acc = 0.f;
        #pragma unroll 8
        for (int d = 0; d < HD_; ++d) acc += wbase[(size_t)d * D_ + e] * cs[d];
        outp[e] = acc * SCALE_;
    }
}

// ---------------------------------------------------------------------------
// C[M,N] = A[M,K] @ B[N,K]^T, fp32 row-major. M,N % 64 == 0, K % 16 == 0.
// 64x64 tile, 256 threads, 4x4 per thread.
__global__ __launch_bounds__(256)
void gemm_tn_kernel(const float* __restrict__ A, const float* __restrict__ Bm,
                    float* __restrict__ Cm, int M, int N, int K) {
    __shared__ float As[64][17];
    __shared__ float Bs[64][17];
    const int tid = threadIdx.x;
    const int row0 = blockIdx.y * 64;
    const int col0 = blockIdx.x * 64;
    const int lr = tid >> 2;           // 0..63
    const int lk = (tid & 3) << 2;     // 0,4,8,12
    const int ty = (tid >> 4) << 2;    // row offset in tile
    const int tx = (tid & 15) << 2;    // col offset in tile
    float acc[4][4] = {{0.f}};
    for (int kk = 0; kk < K; kk += 16) {
        float4 av = *(const float4*)(A  + (size_t)(row0 + lr) * K + kk + lk);
        float4 bv = *(const float4*)(Bm + (size_t)(col0 + lr) * K + kk + lk);
        As[lr][lk+0] = av.x; As[lr][lk+1] = av.y; As[lr][lk+2] = av.z; As[lr][lk+3] = av.w;
        Bs[lr][lk+0] = bv.x; Bs[lr][lk+1] = bv.y; Bs[lr][lk+2] = bv.z; Bs[lr][lk+3] = bv.w;
        __syncthreads();
        #pragma unroll
        for (int k = 0; k < 16; ++k) {
            float a0 = As[ty+0][k], a1 = As[ty+1][k], a2 = As[ty+2][k], a3 = As[ty+3][k];
            float b0 = Bs[tx+0][k], b1 = Bs[tx+1][k], b2 = Bs[tx+2][k], b3 = Bs[tx+3][k];
            acc[0][0] += a0*b0; acc[0][1] += a0*b1; acc[0][2] += a0*b2; acc[0][3] += a0*b3;
            acc[1][0] += a1*b0; acc[1][1] += a1*b1; acc[1][2] += a1*b2; acc[1][3] += a1*b3;
            acc[2][0] += a2*b0; acc[2][1] += a2*b1; acc[2][2] += a2*b2; acc[2][3] += a2*b3;
            acc[3][0] += a3*b0; acc[3][1] += a3*b1; acc[3][2] += a3*b2; acc[3][3] += a3*b3;
        }
        __syncthreads();
    }
    #pragma unroll
    for (int i = 0; i < 4; ++i) {
        float* crow = Cm + (size_t)(row0 + ty + i) * N + col0 + tx;
        *(float4*)crow = make_float4(acc[i][0], acc[i][1], acc[i][2], acc[i][3]);
    }
}

// ---------------------------------------------------------------------------
// Per (b,h,chunk): local sums  ke_loc[c] = sum_t exp(kc[t,c]),
//                               kv_loc[c,d] = sum_t exp(kc[t,c])*v[t,d]
__global__ __launch_bounds__(256)
void chunk_local_kernel(const float* __restrict__ kc, const float* __restrict__ v,
                        float* __restrict__ ke_loc, float* __restrict__ kv_loc) {
    const int bid = blockIdx.x;            // bh*NC_ + chunk
    const int chunk = bid & (NC_ - 1);
    const int bh = bid >> 4;
    const int b = bh >> 4, h = bh & 15;
    const int t0 = chunk * L_;
    const int tid = threadIdx.x;
    __shared__ float ke_s[L_][C_];     // 8 KB
    __shared__ float v_s[L_][HD_];     // 32 KB
    __shared__ float gsum[C_][16];
    #pragma unroll
    for (int r = 0; r < 2; ++r) {
        int flat = r * 1024 + tid * 4;
        int t = flat >> 4, c = flat & 15;
        float4 k4 = *(const float4*)(kc + (size_t)(b * T_ + t0 + t) * NQK_ + h * C_ + c);
        ke_s[t][c+0] = expf(k4.x); ke_s[t][c+1] = expf(k4.y);
        ke_s[t][c+2] = expf(k4.z); ke_s[t][c+3] = expf(k4.w);
    }
    #pragma unroll
    for (int r = 0; r < 8; ++r) {
        int flat = r * 1024 + tid * 4;
        int t = flat >> 6, d = flat & 63;
        *(float4*)&v_s[t][d] = *(const float4*)(v + (size_t)(b * T_ + t0 + t) * D_ + h * HD_ + d);
    }
    __syncthreads();
    const int c = tid >> 4;
    const int dg = (tid & 15) << 2;
    float a0 = 0.f, a1 = 0.f, a2 = 0.f, a3 = 0.f;
    for (int t = 0; t < L_; ++t) {
        float kev = ke_s[t][c];
        float4 vv = *(const float4*)&v_s[t][dg];
        a0 += kev * vv.x; a1 += kev * vv.y; a2 += kev * vv.z; a3 += kev * vv.w;
    }
    {   // two-level ke column sums
        const int cc = tid & 15, g = tid >> 4;
        float s = 0.f;
        #pragma unroll
        for (int u = 0; u < 8; ++u) s += ke_s[g * 8 + u][cc];
        gsum[cc][g] = s;
    }
    __syncthreads();
    if (tid < C_) {
        float s = 0.f;
        #pragma unroll
        for (int g = 0; g < 16; ++g) s += gsum[tid][g];
        ke_loc[(size_t)bid * C_ + tid] = s;
    }
    *(float4*)(kv_loc + (size_t)bid * 1024 + c * HD_ + dg) = make_float4(a0, a1, a2, a3);
}

// ---------------------------------------------------------------------------
// In-place exclusive prefix over the NC_ chunks, per (b,h). 32 blocks.
__global__ __launch_bounds__(1024)
void chunk_scan_kernel(float* __restrict__ ke_loc, float* __restrict__ kv_loc) {
    const int bh = blockIdx.x;
    const int tid = threadIdx.x;   // owns one (c,d) of the 1024
    float run = 0.f;
    for (int ch = 0; ch < NC_; ++ch) {
        size_t idx = ((size_t)(bh * NC_ + ch)) * 1024 + tid;
        float tmp = kv_loc[idx];
        kv_loc[idx] = run;
        run += tmp;
    }
    if (tid < C_) {
        float run2 = 0.f;
        for (int ch = 0; ch < NC_; ++ch) {
            size_t idx = ((size_t)(bh * NC_ + ch)) * C_ + tid;
            float tmp = ke_loc[idx];
            ke_loc[idx] = run2;
            run2 += tmp;
        }
    }
}

// ---------------------------------------------------------------------------
// Per (b,h,chunk): xo[t,d] = sum_c qn[t,c]*S0[c,d] + sum_{s<=t} (qn[t,:].ke[s,:]) v[s,d]
//   qn[t,c] = softmax_c(qc[t,:])*scale / (e0[c] + prefix_ke[t,c] + 1e-9)
__global__ __launch_bounds__(256)
void intra_kernel(const float* __restrict__ qc, const float* __restrict__ kc,
                  const float* __restrict__ v, const float* __restrict__ ke_loc,
                  const float* __restrict__ kv_loc, float* __restrict__ xo) {
    const int bid = blockIdx.x;
    const int chunk = bid & (NC_ - 1);
    const int bh = bid >> 4;
    const int b = bh >> 4, h = bh & 15;
    const int t0 = chunk * L_;
    const int tid = threadIdx.x;
    __shared__ float ke_s[L_][C_];       // 8 KB
    __shared__ float v_s[L_][HD_];       // 32 KB
    __shared__ float S0[C_][HD_];        // 4 KB
    __shared__ float e0[C_];
    __shared__ float gsum[C_][16];
    __shared__ float kesum_s[L_][C_];    // 8 KB
    __shared__ float qn_s[L_][C_];       // 8 KB
    // stage ke (=exp(kc)) and v
    #pragma unroll
    for (int r = 0; r < 2; ++r) {
        int flat = r * 1024 + tid * 4;
        int t = flat >> 4, c = flat & 15;
        float4 k4 = *(const float4*)(kc + (size_t)(b * T_ + t0 + t) * NQK_ + h * C_ + c);
        ke_s[t][c+0] = expf(k4.x); ke_s[t][c+1] = expf(k4.y);
        ke_s[t][c+2] = expf(k4.z); ke_s[t][c+3] = expf(k4.w);
    }
    #pragma unroll
    for (int r = 0; r < 8; ++r) {
        int flat = r * 1024 + tid * 4;
        int t = flat >> 6, d = flat & 63;
        *(float4*)&v_s[t][d] = *(const float4*)(v + (size_t)(b * T_ + t0 + t) * D_ + h * HD_ + d);
    }
    {   // chunk-exclusive state
        float4 s4 = *(const float4*)(kv_loc + (size_t)bid * 1024 + tid * 4);
        *(float4*)&((float*)S0)[tid * 4] = s4;
        if (tid < C_) e0[tid] = ke_loc[(size_t)bid * C_ + tid];
    }
    __syncthreads();
    // two-level inclusive scan of ke over t (plus e0 offset)
    const int cc = tid & 15, g = tid >> 4;
    {
        float s = 0.f;
        #pragma unroll
        for (int u = 0; u < 8; ++u) s += ke_s[g * 8 + u][cc];
        gsum[cc][g] = s;
    }
    __syncthreads();
    if (tid < C_) {
        float run = e0[tid];
        #pragma unroll
        for (int gg = 0; gg < 16; ++gg) { float tmp = gsum[tid][gg]; gsum[tid][gg] = run; run += tmp; }
    }
    __syncthreads();
    {
        float run = gsum[cc][g];
        #pragma unroll
        for (int u = 0; u < 8; ++u) { run += ke_s[g * 8 + u][cc]; kesum_s[g * 8 + u][cc] = run; }
    }
    __syncthreads();
    // qn = softmax(qc)*scale / (kesum + eps)
    if (tid < L_) {
        const int t = tid;
        const float* qrow = qc + (size_t)(b * T_ + t0 + t) * NQK_ + h * C_;
        float qv[C_];
        float m = -1e30f;
        #pragma unroll
        for (int c2 = 0; c2 < C_; ++c2) { qv[c2] = qrow[c2]; m = fmaxf(m, qv[c2]); }
        float sum = 0.f;
        #pragma unroll
        for (int c2 = 0; c2 < C_; ++c2) { qv[c2] = expf(qv[c2] - m); sum += qv[c2]; }
        const float inv = SCALE_ / sum;
        #pragma unroll
        for (int c2 = 0; c2 < C_; ++c2) qn_s[t][c2] = qv[c2] * inv / (kesum_s[t][c2] + 1e-9f);
    }
    __syncthreads();
    // output: thread -> (t = tid/2, half of head dim)
    const int t = tid >> 1;
    const int d0 = (tid & 1) << 5;
    float qnr[C_];
    #pragma unroll
    for (int c2 = 0; c2 < C_; ++c2) qnr[c2] = qn_s[t][c2];
    float acc[32];
    #pragma unroll
    for (int j = 0; j < 32; ++j) acc[j] = 0.f;
    #pragma unroll
    for (int c2 = 0; c2 < C_; ++c2) {
        const float qn = qnr[c2];
        #pragma unroll
        for (int j = 0; j < 32; ++j) acc[j] += qn * S0[c2][d0 + j];
    }
    for (int s = 0; s <= t; ++s) {
        float p = 0.f;
        #pragma unroll
        for (int c2 = 0; c2 < C_; ++c2) p += qnr[c2] * ke_s[s][c2];
        #pragma unroll
        for (int j = 0; j < 32; ++j) acc[j] += p * v_s[s][d0 + j];
    }
    float* orow = xo + (size_t)(b * T_ + t0 + t) * D_ + h * HD_ + d0;
    #pragma unroll
    for (int j = 0; j < 32; j += 4)
        *(float4*)(orow + j) = make_float4(acc[j], acc[j+1], acc[j+2], acc[j+3]);
}

// ---------------------------------------------------------------------------
extern "C" void kernel_launch(void* const* d_in, const int* in_sizes, int n_in,
                              void* d_out, int out_size, void* d_ws, size_t ws_size,
                              hipStream_t stream) {
    const float* x     = (const float*)d_in[0];   // (2,2048,1024)
    const float* w_qkv = (const float*)d_in[1];   // (3072,1024)
    const float* w_out = (const float*)d_in[2];   // (1024,1024)
    const float* code  = (const float*)d_in[3];   // (1,16,16,64)
    float* out = (float*)d_out;                   // (2,2048,1024)

    float* ws = (float*)d_ws;
    float* Wqc    = ws;                     // 256*1024
    float* Wkc    = Wqc + 256 * 1024;       // 256*1024
    float* qcb    = Wkc + 256 * 1024;       // 4096*256
    float* kcb    = qcb + 4096 * 256;       // 4096*256
    float* vb     = kcb + 4096 * 256;       // 4096*1024
    float* xob    = vb  + 4096 * 1024;      // 4096*1024
    float* ke_loc = xob + 4096 * 1024;      // 512*16
    float* kv_loc = ke_loc + 512 * 16;      // 512*1024
    // total: ~46.2 MB of fp32 workspace

    fold_code_kernel<<<512, 256, 0, stream>>>(w_qkv, code, Wqc, Wkc);
    // qc = x @ Wqc^T   (4096 x 256)
    gemm_tn_kernel<<<dim3(4, 64), 256, 0, stream>>>(x, Wqc, qcb, 4096, 256, 1024);
    // kc = x @ Wkc^T   (4096 x 256)
    gemm_tn_kernel<<<dim3(4, 64), 256, 0, stream>>>(x, Wkc, kcb, 4096, 256, 1024);
    // v  = x @ Wv^T    (4096 x 1024), Wv = w_qkv rows 2048..3071
    gemm_tn_kernel<<<dim3(16, 64), 256, 0, stream>>>(x, w_qkv + (size_t)2048 * 1024, vb, 4096, 1024, 1024);
    // chunked linear attention
    chunk_local_kernel<<<512, 256, 0, stream>>>(kcb, vb, ke_loc, kv_loc);
    chunk_scan_kernel<<<32, 1024, 0, stream>>>(ke_loc, kv_loc);
    intra_kernel<<<512, 256, 0, stream>>>(qcb, kcb, vb, ke_loc, kv_loc, xob);
    // out = xo @ w_out^T  (4096 x 1024)
    gemm_tn_kernel<<<dim3(16, 64), 256, 0, stream>>>(xob, w_out, out, 4096, 1024, 1024);
}

// Round 2
// 125.205 us; speedup vs baseline: 4.8396x; 4.8396x over previous
//
#include <hip/hip_runtime.h>
#include <math.h>

// Problem constants (B=2, T=2048, D=1024, H=16, HD=64, C=16)
#define B_    2
#define T_    2048
#define D_    1024
#define H_    16
#define HD_   64
#define C_    16
#define SCALE_ 0.125f      // HEAD_DIM^-0.5
#define L_    128          // time-chunk length
#define NC_   16           // T_/L_
#define NW_   1536         // fused qc|kc|v width

typedef __attribute__((ext_vector_type(8))) short short8;
typedef __attribute__((ext_vector_type(4))) float f32x4;

__device__ inline float b2f(uint32_t u16) {
    return __uint_as_float(u16 << 16);
}
__device__ inline ushort f2b(float f) {   // RNE
    uint32_t u = __float_as_uint(f);
    return (ushort)((u + 0x7FFFu + ((u >> 16) & 1u)) >> 16);
}
__device__ inline uint32_t pack2(float a, float b) {
    return (uint32_t)f2b(a) | ((uint32_t)f2b(b) << 16);
}
__device__ inline void unpack8(uint4 raw, float* dst) {
    uint32_t w0 = raw.x, w1 = raw.y, w2 = raw.z, w3 = raw.w;
    dst[0] = b2f(w0 & 0xffffu); dst[1] = __uint_as_float(w0 & 0xffff0000u);
    dst[2] = b2f(w1 & 0xffffu); dst[3] = __uint_as_float(w1 & 0xffff0000u);
    dst[4] = b2f(w2 & 0xffffu); dst[5] = __uint_as_float(w2 & 0xffff0000u);
    dst[6] = b2f(w3 & 0xffffu); dst[7] = __uint_as_float(w3 & 0xffff0000u);
}

// ---------------------------------------------------------------------------
// generic fp32 -> bf16 cast, 8 elems/thread
__global__ __launch_bounds__(256)
void cast_bf16_kernel(const float* __restrict__ in, ushort* __restrict__ out, int n) {
    int i = (blockIdx.x * 256 + threadIdx.x) * 8;
    if (i >= n) return;
    float4 a = *(const float4*)(in + i);
    float4 b = *(const float4*)(in + i + 4);
    uint4 o;
    o.x = pack2(a.x, a.y); o.y = pack2(a.z, a.w);
    o.z = pack2(b.x, b.y); o.w = pack2(b.z, b.w);
    *(uint4*)(out + i) = o;
}

// ---------------------------------------------------------------------------
// Fold fc_code into the q/k slices of w_qkv, write bf16 rows 0..511 of W_all:
//   W_all[isK*256 + h*16+c, e] = scale * sum_d w_qkv[isK*1024 + h*64+d, e] * code[h,c,d]
__global__ __launch_bounds__(256)
void fold_code_kernel(const float* __restrict__ w_qkv, const float* __restrict__ code,
                      ushort* __restrict__ WallB) {
    const int bid = blockIdx.x;      // 0..511
    const int isK = bid >> 8;        // 0 => q, 1 => k
    const int row = bid & 255;       // h*16+c
    const int h = row >> 4;
    __shared__ float cs[HD_];
    if (threadIdx.x < HD_) cs[threadIdx.x] = code[row * HD_ + threadIdx.x];
    __syncthreads();
    const float* wbase = w_qkv + (size_t)(isK * D_ + h * HD_) * D_;
    ushort* outp = WallB + (size_t)(isK * 256 + row) * D_;
    for (int e = threadIdx.x; e < D_; e += 256) {
        float acc = 0.f;
        #pragma unroll 8
        for (int d = 0; d < HD_; ++d) acc += wbase[(size_t)d * D_ + e] * cs[d];
        outp[e] = f2b(acc * SCALE_);
    }
}

// ---------------------------------------------------------------------------
// bf16 MFMA GEMM: C[M,N] = A[M,K] @ B[N,K]^T. 128x128 tile, BK=64, 4 waves.
// A,B bf16 row-major [.][K]; C fp32 (WRITE_BF16=0) or bf16 (WRITE_BF16=1).
// LDS: linear dest for global_load_lds; XOR slot-swizzle applied to the
// pre-swizzled global source AND the ds_read address (both-sides rule).
template<int WRITE_BF16>
__global__ __launch_bounds__(256)
void gemm_bf16_kernel(const ushort* __restrict__ A, const ushort* __restrict__ Bw,
                      void* __restrict__ Cv, int M, int N, int K) {
    __shared__ ushort As[128 * 64];   // 16 KB
    __shared__ ushort Bs[128 * 64];   // 16 KB
    const int tid  = threadIdx.x;
    const int wave = tid >> 6;
    const int lane = tid & 63;
    const int wr = wave >> 1, wc = wave & 1;
    const int row0 = blockIdx.y * 128;
    const int col0 = blockIdx.x * 128;

    f32x4 acc[4][4];
    #pragma unroll
    for (int m = 0; m < 4; ++m)
        #pragma unroll
        for (int n = 0; n < 4; ++n) acc[m][n] = (f32x4){0.f, 0.f, 0.f, 0.f};

    // staging constants (per lane): dest byte d = seg*1024 + lane*16 (linear)
    // r = d>>7 = seg*8 + (lane>>3);  r&7 = lane>>3  (seg*8 cancels)
    // source elem offset within row: k = (((lane&7) ^ (lane>>3)) << 3)
    const int srow = lane >> 3;
    const int kA   = ((lane & 7) ^ srow) << 3;

    // fragment-read constants
    const int lane15 = lane & 15;
    const int lhi    = lane >> 4;           // 0..3
    const int axor   = (lane15 & 7) << 4;   // == (r&7)<<4 for fragment rows
    const char* Ab = (const char*)As;
    const char* Bb = (const char*)Bs;

    for (int kk = 0; kk < K; kk += 64) {
        // ---- stage next tile (4 A-segments + 4 B-segments per wave) ----
        #pragma unroll
        for (int i = 0; i < 4; ++i) {
            const int seg = wave * 4 + i;
            const int r = seg * 8 + srow;
            const ushort* ga = A  + (size_t)(row0 + r) * K + kk + kA;
            const ushort* gb = Bw + (size_t)(col0 + r) * K + kk + kA;
            __builtin_amdgcn_global_load_lds(
                (const __attribute__((address_space(1))) void*)ga,
                (__attribute__((address_space(3))) void*)&As[seg * 512], 16, 0, 0);
            __builtin_amdgcn_global_load_lds(
                (const __attribute__((address_space(1))) void*)gb,
                (__attribute__((address_space(3))) void*)&Bs[seg * 512], 16, 0, 0);
        }
        __syncthreads();   // compiler drains vmcnt(0) before s_barrier

        // ---- compute: 2 k-steps x 16 MFMA ----
        #pragma unroll
        for (int s = 0; s < 2; ++s) {
            short8 af[4], bf[4];
            #pragma unroll
            for (int m = 0; m < 4; ++m) {
                const int r = wr * 64 + m * 16 + lane15;
                const int off = (r * 128 + s * 64 + lhi * 16) ^ axor;
                af[m] = *(const short8*)(Ab + off);
            }
            #pragma unroll
            for (int n = 0; n < 4; ++n) {
                const int r = wc * 64 + n * 16 + lane15;
                const int off = (r * 128 + s * 64 + lhi * 16) ^ axor;
                bf[n] = *(const short8*)(Bb + off);
            }
            #pragma unroll
            for (int m = 0; m < 4; ++m)
                #pragma unroll
                for (int n = 0; n < 4; ++n)
                    acc[m][n] = __builtin_amdgcn_mfma_f32_16x16x32_bf16(
                        af[m], bf[n], acc[m][n], 0, 0, 0);
        }
        __syncthreads();
    }

    // ---- epilogue: C/D map col=lane&15, row=(lane>>4)*4+j (verified m89) ----
    #pragma unroll
    for (int m = 0; m < 4; ++m) {
        #pragma unroll
        for (int n = 0; n < 4; ++n) {
            const int row = row0 + wr * 64 + m * 16 + lhi * 4;
            const int col = col0 + wc * 64 + n * 16 + lane15;
            if (WRITE_BF16) {
                ushort* C = (ushort*)Cv;
                #pragma unroll
                for (int j = 0; j < 4; ++j)
                    C[(size_t)(row + j) * N + col] = f2b(acc[m][n][j]);
            } else {
                float* C = (float*)Cv;
                #pragma unroll
                for (int j = 0; j < 4; ++j)
                    C[(size_t)(row + j) * N + col] = acc[m][n][j];
            }
        }
    }
}

// ---------------------------------------------------------------------------
// qkcv layout per row t (bf16, stride 1536): [qc(256) | kc(256) | v(1024)]
// Per (b,h,chunk): ke_loc[c] = sum_t exp(kc[t,c]); kv_loc[c,d] = sum_t exp(kc[t,c])*v[t,d]
__global__ __launch_bounds__(256)
void chunk_local_kernel(const ushort* __restrict__ qkcv,
                        float* __restrict__ ke_loc, float* __restrict__ kv_loc) {
    const int bid = blockIdx.x;            // bh*NC_ + chunk
    const int chunk = bid & (NC_ - 1);
    const int bh = bid >> 4;
    const int b = bh >> 4, h = bh & 15;
    const int t0 = chunk * L_;
    const int tid = threadIdx.x;
    __shared__ float ke_s[L_][C_];
    __shared__ float v_s[L_][HD_];
    __shared__ float gsum[C_][16];
    {   // ke: 2048 elems, 8/thread
        const int flat = tid * 8;
        const int t = flat >> 4, c0 = flat & 15;
        uint4 raw = *(const uint4*)(qkcv + (size_t)(b * T_ + t0 + t) * NW_ + 256 + h * C_ + c0);
        float tmp[8]; unpack8(raw, tmp);
        #pragma unroll
        for (int j = 0; j < 8; ++j) ke_s[t][c0 + j] = __expf(tmp[j]);
    }
    #pragma unroll
    for (int r = 0; r < 4; ++r) {   // v: 8192 elems, 32/thread
        const int flat = r * 2048 + tid * 8;
        const int t = flat >> 6, d0 = flat & 63;
        uint4 raw = *(const uint4*)(qkcv + (size_t)(b * T_ + t0 + t) * NW_ + 512 + h * HD_ + d0);
        unpack8(raw, &v_s[t][d0]);
    }
    __syncthreads();
    const int c = tid >> 4;
    const int dg = (tid & 15) << 2;
    float a0 = 0.f, a1 = 0.f, a2 = 0.f, a3 = 0.f;
    for (int t = 0; t < L_; ++t) {
        float kev = ke_s[t][c];
        float4 vv = *(const float4*)&v_s[t][dg];
        a0 += kev * vv.x; a1 += kev * vv.y; a2 += kev * vv.z; a3 += kev * vv.w;
    }
    {   // two-level ke column sums
        const int cc = tid & 15, g = tid >> 4;
        float s = 0.f;
        #pragma unroll
        for (int u = 0; u < 8; ++u) s += ke_s[g * 8 + u][cc];
        gsum[cc][g] = s;
    }
    __syncthreads();
    if (tid < C_) {
        float s = 0.f;
        #pragma unroll
        for (int g = 0; g < 16; ++g) s += gsum[tid][g];
        ke_loc[(size_t)bid * C_ + tid] = s;
    }
    *(float4*)(kv_loc + (size_t)bid * 1024 + c * HD_ + dg) = make_float4(a0, a1, a2, a3);
}

// ---------------------------------------------------------------------------
// In-place exclusive prefix over the NC_ chunks, per (b,h). 32 blocks.
__global__ __launch_bounds__(1024)
void chunk_scan_kernel(float* __restrict__ ke_loc, float* __restrict__ kv_loc) {
    const int bh = blockIdx.x;
    const int tid = threadIdx.x;
    float run = 0.f;
    for (int ch = 0; ch < NC_; ++ch) {
        size_t idx = ((size_t)(bh * NC_ + ch)) * 1024 + tid;
        float tmp = kv_loc[idx];
        kv_loc[idx] = run;
        run += tmp;
    }
    if (tid < C_) {
        float run2 = 0.f;
        for (int ch = 0; ch < NC_; ++ch) {
            size_t idx = ((size_t)(bh * NC_ + ch)) * C_ + tid;
            float tmp = ke_loc[idx];
            ke_loc[idx] = run2;
            run2 += tmp;
        }
    }
}

// ---------------------------------------------------------------------------
// Per (b,h,chunk): xo[t,d] = sum_c qn[t,c]*S0[c,d] + sum_{s<=t} (qn[t,:].ke[s,:]) v[s,d]
//   qn[t,c] = softmax_c(qc[t,:])*scale / (e0[c] + prefix_ke[t,c] + 1e-9)
// Writes xo in bf16.
__global__ __launch_bounds__(256)
void intra_kernel(const ushort* __restrict__ qkcv, const float* __restrict__ ke_loc,
                  const float* __restrict__ kv_loc, ushort* __restrict__ xob) {
    const int bid = blockIdx.x;
    const int chunk = bid & (NC_ - 1);
    const int bh = bid >> 4;
    const int b = bh >> 4, h = bh & 15;
    const int t0 = chunk * L_;
    const int tid = threadIdx.x;
    __shared__ float ke_s[L_][C_];
    __shared__ float v_s[L_][HD_];
    __shared__ float S0[C_][HD_];
    __shared__ float e0[C_];
    __shared__ float gsum[C_][16];
    __shared__ float kesum_s[L_][C_];
    __shared__ float qn_s[L_][C_];
    {   // ke
        const int flat = tid * 8;
        const int t = flat >> 4, c0 = flat & 15;
        uint4 raw = *(const uint4*)(qkcv + (size_t)(b * T_ + t0 + t) * NW_ + 256 + h * C_ + c0);
        float tmp[8]; unpack8(raw, tmp);
        #pragma unroll
        for (int j = 0; j < 8; ++j) ke_s[t][c0 + j] = __expf(tmp[j]);
    }
    #pragma unroll
    for (int r = 0; r < 4; ++r) {   // v
        const int flat = r * 2048 + tid * 8;
        const int t = flat >> 6, d0 = flat & 63;
        uint4 raw = *(const uint4*)(qkcv + (size_t)(b * T_ + t0 + t) * NW_ + 512 + h * HD_ + d0);
        unpack8(raw, &v_s[t][d0]);
    }
    {   // chunk-exclusive state
        float4 s4 = *(const float4*)(kv_loc + (size_t)bid * 1024 + tid * 4);
        *(float4*)&((float*)S0)[tid * 4] = s4;
        if (tid < C_) e0[tid] = ke_loc[(size_t)bid * C_ + tid];
    }
    __syncthreads();
    // two-level inclusive scan of ke over t (plus e0 offset)
    const int cc = tid & 15, g = tid >> 4;
    {
        float s = 0.f;
        #pragma unroll
        for (int u = 0; u < 8; ++u) s += ke_s[g * 8 + u][cc];
        gsum[cc][g] = s;
    }
    __syncthreads();
    if (tid < C_) {
        float run = e0[tid];
        #pragma unroll
        for (int gg = 0; gg < 16; ++gg) { float tmp = gsum[tid][gg]; gsum[tid][gg] = run; run += tmp; }
    }
    __syncthreads();
    {
        float run = gsum[cc][g];
        #pragma unroll
        for (int u = 0; u < 8; ++u) { run += ke_s[g * 8 + u][cc]; kesum_s[g * 8 + u][cc] = run; }
    }
    __syncthreads();
    // qn = softmax(qc)*scale / (kesum + eps)
    if (tid < L_) {
        const int t = tid;
        const ushort* qrow = qkcv + (size_t)(b * T_ + t0 + t) * NW_ + h * C_;
        float qv[C_];
        uint4 r0 = *(const uint4*)qrow;
        uint4 r1 = *(const uint4*)(qrow + 8);
        unpack8(r0, qv); unpack8(r1, qv + 8);
        float m = -1e30f;
        #pragma unroll
        for (int c2 = 0; c2 < C_; ++c2) m = fmaxf(m, qv[c2]);
        float sum = 0.f;
        #pragma unroll
        for (int c2 = 0; c2 < C_; ++c2) { qv[c2] = __expf(qv[c2] - m); sum += qv[c2]; }
        const float inv = SCALE_ / sum;
        #pragma unroll
        for (int c2 = 0; c2 < C_; ++c2) qn_s[t][c2] = qv[c2] * inv / (kesum_s[t][c2] + 1e-9f);
    }
    __syncthreads();
    // output: thread -> (t = tid/2, half of head dim)
    const int t = tid >> 1;
    const int d0 = (tid & 1) << 5;
    float qnr[C_];
    #pragma unroll
    for (int c2 = 0; c2 < C_; ++c2) qnr[c2] = qn_s[t][c2];
    float acc[32];
    #pragma unroll
    for (int j = 0; j < 32; ++j) acc[j] = 0.f;
    #pragma unroll
    for (int c2 = 0; c2 < C_; ++c2) {
        const float qn = qnr[c2];
        #pragma unroll
        for (int j = 0; j < 32; ++j) acc[j] += qn * S0[c2][d0 + j];
    }
    for (int s = 0; s <= t; ++s) {
        float p = 0.f;
        #pragma unroll
        for (int c2 = 0; c2 < C_; ++c2) p += qnr[c2] * ke_s[s][c2];
        #pragma unroll
        for (int j = 0; j < 32; ++j) acc[j] += p * v_s[s][d0 + j];
    }
    ushort* orow = xob + (size_t)(b * T_ + t0 + t) * D_ + h * HD_ + d0;
    #pragma unroll
    for (int j = 0; j < 32; j += 8) {
        uint4 o;
        o.x = pack2(acc[j + 0], acc[j + 1]); o.y = pack2(acc[j + 2], acc[j + 3]);
        o.z = pack2(acc[j + 4], acc[j + 5]); o.w = pack2(acc[j + 6], acc[j + 7]);
        *(uint4*)(orow + j) = o;
    }
}

// ---------------------------------------------------------------------------
extern "C" void kernel_launch(void* const* d_in, const int* in_sizes, int n_in,
                              void* d_out, int out_size, void* d_ws, size_t ws_size,
                              hipStream_t stream) {
    const float* x     = (const float*)d_in[0];   // (2,2048,1024)
    const float* w_qkv = (const float*)d_in[1];   // (3072,1024)
    const float* w_out = (const float*)d_in[2];   // (1024,1024)
    const float* code  = (const float*)d_in[3];   // (1,16,16,64)
    float* out = (float*)d_out;                   // (2,2048,1024)

    ushort* xb    = (ushort*)d_ws;                    // 4096*1024
    ushort* WallB = xb + (size_t)4096 * 1024;         // 1536*1024
    ushort* WoB   = WallB + (size_t)1536 * 1024;      // 1024*1024
    ushort* qkcv  = WoB + (size_t)1024 * 1024;        // 4096*1536
    ushort* xob   = qkcv + (size_t)4096 * 1536;       // 4096*1024
    float*  ke_loc = (float*)(xob + (size_t)4096 * 1024);  // 512*16
    float*  kv_loc = ke_loc + 512 * 16;               // 512*1024
    // total ~35.7 MB

    // casts + weight folding
    cast_bf16_kernel<<<2048, 256, 0, stream>>>(x, xb, 4096 * 1024);
    cast_bf16_kernel<<<512, 256, 0, stream>>>(w_qkv + (size_t)2048 * 1024,
                                              WallB + (size_t)512 * 1024, 1024 * 1024);
    cast_bf16_kernel<<<512, 256, 0, stream>>>(w_out, WoB, 1024 * 1024);
    fold_code_kernel<<<512, 256, 0, stream>>>(w_qkv, code, WallB);

    // fused qc|kc|v projection: (4096 x 1536 x 1024), bf16 out
    gemm_bf16_kernel<1><<<dim3(12, 32), 256, 0, stream>>>(xb, WallB, qkcv, 4096, NW_, 1024);

    // chunked linear attention
    chunk_local_kernel<<<512, 256, 0, stream>>>(qkcv, ke_loc, kv_loc);
    chunk_scan_kernel<<<32, 1024, 0, stream>>>(ke_loc, kv_loc);
    intra_kernel<<<512, 256, 0, stream>>>(qkcv, ke_loc, kv_loc, xob);

    // out = xo @ w_out^T  (4096 x 1024 x 1024), fp32 out
    gemm_bf16_kernel<0><<<dim3(8, 32), 256, 0, stream>>>(xob, WoB, out, 4096, 1024, 1024);
}

// Round 3
// 103.501 us; speedup vs baseline: 5.8544x; 1.2097x over previous
//
#include <hip/hip_runtime.h>
#include <math.h>

// Problem constants (B=2, T=2048, D=1024, H=16, HD=64, C=16)
#define B_    2
#define T_    2048
#define D_    1024
#define H_    16
#define HD_   64
#define C_    16
#define SCALE_ 0.125f      // HEAD_DIM^-0.5
#define L_    128          // time-chunk length
#define NC_   16           // T_/L_
#define NW_   1536         // fused qc|kc|v width

typedef __attribute__((ext_vector_type(8))) short short8;
typedef __attribute__((ext_vector_type(4))) float f32x4;

__device__ inline float b2f(uint32_t u16) {
    return __uint_as_float(u16 << 16);
}
__device__ inline ushort f2b(float f) {   // RNE
    uint32_t u = __float_as_uint(f);
    return (ushort)((u + 0x7FFFu + ((u >> 16) & 1u)) >> 16);
}
__device__ inline uint32_t pack2(float a, float b) {
    return (uint32_t)f2b(a) | ((uint32_t)f2b(b) << 16);
}
__device__ inline void unpack2(uint32_t w, float& a, float& b) {
    a = b2f(w & 0xffffu); b = __uint_as_float(w & 0xffff0000u);
}
__device__ inline void unpack8(uint4 raw, float* dst) {
    unpack2(raw.x, dst[0], dst[1]);
    unpack2(raw.y, dst[2], dst[3]);
    unpack2(raw.z, dst[4], dst[5]);
    unpack2(raw.w, dst[6], dst[7]);
}

// ---------------------------------------------------------------------------
// generic fp32 -> bf16 cast, 8 elems/thread
__global__ __launch_bounds__(256)
void cast_bf16_kernel(const float* __restrict__ in, ushort* __restrict__ out, int n) {
    int i = (blockIdx.x * 256 + threadIdx.x) * 8;
    if (i >= n) return;
    float4 a = *(const float4*)(in + i);
    float4 b = *(const float4*)(in + i + 4);
    uint4 o;
    o.x = pack2(a.x, a.y); o.y = pack2(a.z, a.w);
    o.z = pack2(b.x, b.y); o.w = pack2(b.z, b.w);
    *(uint4*)(out + i) = o;
}

// ---------------------------------------------------------------------------
// Fold fc_code into the q/k slices of w_qkv, write bf16 rows 0..511 of W_all
__global__ __launch_bounds__(256)
void fold_code_kernel(const float* __restrict__ w_qkv, const float* __restrict__ code,
                      ushort* __restrict__ WallB) {
    const int bid = blockIdx.x;      // 0..511
    const int isK = bid >> 8;
    const int row = bid & 255;       // h*16+c
    const int h = row >> 4;
    __shared__ float cs[HD_];
    if (threadIdx.x < HD_) cs[threadIdx.x] = code[row * HD_ + threadIdx.x];
    __syncthreads();
    const float* wbase = w_qkv + (size_t)(isK * D_ + h * HD_) * D_;
    ushort* outp = WallB + (size_t)(isK * 256 + row) * D_;
    for (int e = threadIdx.x; e < D_; e += 256) {
        float acc = 0.f;
        #pragma unroll 8
        for (int d = 0; d < HD_; ++d) acc += wbase[(size_t)d * D_ + e] * cs[d];
        outp[e] = f2b(acc * SCALE_);
    }
}

// ---------------------------------------------------------------------------
// bf16 MFMA GEMM: C[M,N] = A[M,K] @ B[N,K]^T. 128x128 tile, BK=64, 4 waves.
template<int WRITE_BF16>
__global__ __launch_bounds__(256)
void gemm_bf16_kernel(const ushort* __restrict__ A, const ushort* __restrict__ Bw,
                      void* __restrict__ Cv, int M, int N, int K) {
    __shared__ ushort As[128 * 64];
    __shared__ ushort Bs[128 * 64];
    const int tid  = threadIdx.x;
    const int wave = tid >> 6;
    const int lane = tid & 63;
    const int wr = wave >> 1, wc = wave & 1;
    const int row0 = blockIdx.y * 128;
    const int col0 = blockIdx.x * 128;

    f32x4 acc[4][4];
    #pragma unroll
    for (int m = 0; m < 4; ++m)
        #pragma unroll
        for (int n = 0; n < 4; ++n) acc[m][n] = (f32x4){0.f, 0.f, 0.f, 0.f};

    const int srow = lane >> 3;
    const int kA   = ((lane & 7) ^ srow) << 3;

    const int lane15 = lane & 15;
    const int lhi    = lane >> 4;
    const int axor   = (lane15 & 7) << 4;
    const char* Ab = (const char*)As;
    const char* Bb = (const char*)Bs;

    for (int kk = 0; kk < K; kk += 64) {
        #pragma unroll
        for (int i = 0; i < 4; ++i) {
            const int seg = wave * 4 + i;
            const int r = seg * 8 + srow;
            const ushort* ga = A  + (size_t)(row0 + r) * K + kk + kA;
            const ushort* gb = Bw + (size_t)(col0 + r) * K + kk + kA;
            __builtin_amdgcn_global_load_lds(
                (const __attribute__((address_space(1))) void*)ga,
                (__attribute__((address_space(3))) void*)&As[seg * 512], 16, 0, 0);
            __builtin_amdgcn_global_load_lds(
                (const __attribute__((address_space(1))) void*)gb,
                (__attribute__((address_space(3))) void*)&Bs[seg * 512], 16, 0, 0);
        }
        __syncthreads();

        #pragma unroll
        for (int s = 0; s < 2; ++s) {
            short8 af[4], bf[4];
            #pragma unroll
            for (int m = 0; m < 4; ++m) {
                const int r = wr * 64 + m * 16 + lane15;
                const int off = (r * 128 + s * 64 + lhi * 16) ^ axor;
                af[m] = *(const short8*)(Ab + off);
            }
            #pragma unroll
            for (int n = 0; n < 4; ++n) {
                const int r = wc * 64 + n * 16 + lane15;
                const int off = (r * 128 + s * 64 + lhi * 16) ^ axor;
                bf[n] = *(const short8*)(Bb + off);
            }
            #pragma unroll
            for (int m = 0; m < 4; ++m)
                #pragma unroll
                for (int n = 0; n < 4; ++n)
                    acc[m][n] = __builtin_amdgcn_mfma_f32_16x16x32_bf16(
                        af[m], bf[n], acc[m][n], 0, 0, 0);
        }
        __syncthreads();
    }

    #pragma unroll
    for (int m = 0; m < 4; ++m) {
        #pragma unroll
        for (int n = 0; n < 4; ++n) {
            const int row = row0 + wr * 64 + m * 16 + lhi * 4;
            const int col = col0 + wc * 64 + n * 16 + lane15;
            if (WRITE_BF16) {
                ushort* C = (ushort*)Cv;
                #pragma unroll
                for (int j = 0; j < 4; ++j)
                    C[(size_t)(row + j) * N + col] = f2b(acc[m][n][j]);
            } else {
                float* C = (float*)Cv;
                #pragma unroll
                for (int j = 0; j < 4; ++j)
                    C[(size_t)(row + j) * N + col] = acc[m][n][j];
            }
        }
    }
}

// ---------------------------------------------------------------------------
// Transpose v slice of qkcv -> vT[bh][d][t]  (per bh: 64 x 2048, bf16)
__global__ __launch_bounds__(256)
void vtrans_kernel(const ushort* __restrict__ qkcv, ushort* __restrict__ vT) {
    const int bh = blockIdx.x, tb = blockIdx.y;
    const int b = bh >> 4, h = bh & 15;
    const int tid = threadIdx.x;
    __shared__ __align__(16) ushort tile[128 * 64];
    char* tB = (char*)tile;
    #pragma unroll
    for (int r = 0; r < 4; ++r) {
        const int idx = r * 2048 + tid * 8;
        const int t = idx >> 6, d0 = idx & 63;
        uint4 raw = *(const uint4*)(qkcv + (size_t)(b * T_ + tb * 128 + t) * NW_ + 512 + h * 64 + d0);
        *(uint4*)(tB + ((t * 128 + d0 * 2) ^ (((t >> 3) & 7) << 4))) = raw;
    }
    __syncthreads();
    const int d = tid >> 2, tq = tid & 3;
    ushort* obase = vT + ((size_t)bh * 64 + d) * 2048 + tb * 128;
    #pragma unroll
    for (int c8 = 0; c8 < 4; ++c8) {
        const int tA = c8 * 32 + tq * 8;
        uint32_t w[4];
        #pragma unroll
        for (int p = 0; p < 4; ++p) {
            const int tL = tA + p * 2;
            uint32_t lo = *(const ushort*)(tB + ((tL * 128 + d * 2) ^ (((tL >> 3) & 7) << 4)));
            uint32_t hi = *(const ushort*)(tB + (((tL + 1) * 128 + d * 2) ^ ((((tL + 1) >> 3) & 7) << 4)));
            w[p] = lo | (hi << 16);
        }
        uint4 o; o.x = w[0]; o.y = w[1]; o.z = w[2]; o.w = w[3];
        *(uint4*)(obase + tA) = o;
    }
}

// ---------------------------------------------------------------------------
// Per (b,h,chunk): ke_loc[c] = sum_t exp(kc[t,c]); kv_loc[c,d] = sum_t exp(kc[t,c])*v[t,d]
__global__ __launch_bounds__(256)
void chunk_local_kernel(const ushort* __restrict__ qkcv,
                        float* __restrict__ ke_loc, float* __restrict__ kv_loc) {
    const int bid = blockIdx.x;
    const int chunk = bid & (NC_ - 1);
    const int bh = bid >> 4;
    const int b = bh >> 4, h = bh & 15;
    const int t0 = chunk * L_;
    const int tid = threadIdx.x;
    __shared__ float ke_s[L_][C_];
    __shared__ __align__(16) ushort v_s[L_][HD_];
    __shared__ float gsum[C_][16];
    {   // ke: 2048 elems, 8/thread, exp in fp32
        const int t = tid >> 1, c0 = (tid & 1) * 8;
        uint4 raw = *(const uint4*)(qkcv + (size_t)(b * T_ + t0 + t) * NW_ + 256 + h * C_ + c0);
        float f[8]; unpack8(raw, f);
        #pragma unroll
        for (int j = 0; j < 8; ++j) ke_s[t][c0 + j] = __expf(f[j]);
    }
    #pragma unroll
    for (int r = 0; r < 4; ++r) {   // v: raw bf16 copy, 32/thread
        const int idx = r * 2048 + tid * 8;
        const int t = idx >> 6, d0 = idx & 63;
        *(uint4*)&v_s[t][d0] =
            *(const uint4*)(qkcv + (size_t)(b * T_ + t0 + t) * NW_ + 512 + h * HD_ + d0);
    }
    __syncthreads();
    const int c = tid >> 4;
    const int dg = (tid & 15) << 2;
    float a0 = 0.f, a1 = 0.f, a2 = 0.f, a3 = 0.f;
    for (int t = 0; t < L_; ++t) {
        float kev = ke_s[t][c];
        uint2 rv = *(const uint2*)&v_s[t][dg];
        float v0, v1, v2, v3;
        unpack2(rv.x, v0, v1); unpack2(rv.y, v2, v3);
        a0 += kev * v0; a1 += kev * v1; a2 += kev * v2; a3 += kev * v3;
    }
    {
        const int cc = tid & 15, g = tid >> 4;
        float s = 0.f;
        #pragma unroll
        for (int u = 0; u < 8; ++u) s += ke_s[g * 8 + u][cc];
        gsum[cc][g] = s;
    }
    __syncthreads();
    if (tid < C_) {
        float s = 0.f;
        #pragma unroll
        for (int g = 0; g < 16; ++g) s += gsum[tid][g];
        ke_loc[(size_t)bid * C_ + tid] = s;
    }
    *(float4*)(kv_loc + (size_t)bid * 1024 + c * HD_ + dg) = make_float4(a0, a1, a2, a3);
}

// ---------------------------------------------------------------------------
// In-place exclusive prefix over the NC_ chunks, per (b,h). 32 blocks.
__global__ __launch_bounds__(1024)
void chunk_scan_kernel(float* __restrict__ ke_loc, float* __restrict__ kv_loc) {
    const int bh = blockIdx.x;
    const int tid = threadIdx.x;
    float run = 0.f;
    for (int ch = 0; ch < NC_; ++ch) {
        size_t idx = ((size_t)(bh * NC_ + ch)) * 1024 + tid;
        float tmp = kv_loc[idx];
        kv_loc[idx] = run;
        run += tmp;
    }
    if (tid < C_) {
        float run2 = 0.f;
        for (int ch = 0; ch < NC_; ++ch) {
            size_t idx = ((size_t)(bh * NC_ + ch)) * C_ + tid;
            float tmp = ke_loc[idx];
            ke_loc[idx] = run2;
            run2 += tmp;
        }
    }
}

// ---------------------------------------------------------------------------
// MFMA intra: per (b,h,chunk):
//   P^T = Ke·Qn^T (16x16x32, K zero-padded), causal mask, P -> swizzled LDS bf16
//   O = Qn·S0 + P·V  (V from pre-transposed vT)
__global__ __launch_bounds__(256)
void intra_kernel(const ushort* __restrict__ qkcv, const ushort* __restrict__ vT,
                  const float* __restrict__ ke_loc, const float* __restrict__ kv_loc,
                  ushort* __restrict__ xob) {
    const int bid = blockIdx.x;
    const int chunk = bid & (NC_ - 1);
    const int bh = bid >> 4;
    const int b = bh >> 4, h = bh & 15;
    const int t0 = chunk * L_;
    const int tid = threadIdx.x;
    const int wave = tid >> 6, lane = tid & 63;
    const int l15 = lane & 15, lhi = lane >> 4;

    __shared__ __align__(16) ushort ke_bf[128 * 32];   // [t][c] c-padded to 32, swz ((t>>1)&3)<<4
    __shared__ __align__(16) ushort qn_bf[128 * 32];   // same layout
    __shared__ __align__(16) ushort Vt_s[64 * 128];    // [d][s], swz (d&15)<<4
    __shared__ __align__(16) ushort Pl[128 * 128];     // [t][s], swz (t&15)<<4
    __shared__ __align__(16) ushort S0t[64 * 32];      // [d][c] padded, swz ((d>>1)&3)<<4
    __shared__ float kesum_s[128][16];
    __shared__ float gsum[16][16];
    __shared__ float e0s[16];

    char* keB = (char*)ke_bf;
    char* qnB = (char*)qn_bf;
    char* vtB = (char*)Vt_s;
    char* plB = (char*)Pl;
    char* s0B = (char*)S0t;

    // ---- stage ke = exp(kc) as bf16 (+ zero pad) ----
    {
        const int t = tid >> 1, c0 = (tid & 1) * 8;
        uint4 raw = *(const uint4*)(qkcv + (size_t)(b * T_ + t0 + t) * NW_ + 256 + h * C_ + c0);
        float f[8]; unpack8(raw, f);
        uint4 o;
        o.x = pack2(__expf(f[0]), __expf(f[1]));
        o.y = pack2(__expf(f[2]), __expf(f[3]));
        o.z = pack2(__expf(f[4]), __expf(f[5]));
        o.w = pack2(__expf(f[6]), __expf(f[7]));
        const int swz = ((t >> 1) & 3) << 4;
        *(uint4*)(keB + ((t * 64 + c0 * 2) ^ swz)) = o;
        *(uint4*)(keB + ((t * 64 + 32 + c0 * 2) ^ swz)) = make_uint4(0, 0, 0, 0);
    }
    // ---- stage Vt (bf16 [d][s] swizzled) from vT global ----
    {
        const int d = tid >> 2, q = tid & 3;
        const ushort* src = vT + ((size_t)bh * 64 + d) * 2048 + t0 + q * 32;
        const int swz = (d & 15) << 4;
        #pragma unroll
        for (int i = 0; i < 4; ++i) {
            uint4 raw = *(const uint4*)(src + i * 8);
            *(uint4*)(vtB + ((d * 256 + q * 64 + i * 16) ^ swz)) = raw;
        }
    }
    // ---- stage S0t = kv_loc^T (bf16 padded) + zero pad + e0 ----
    {
        const int c = tid >> 4;
        const int d0 = (tid & 15) * 4;
        float4 s4 = *(const float4*)(kv_loc + (size_t)bid * 1024 + c * 64 + d0);
        const float* sp = (const float*)&s4;
        #pragma unroll
        for (int j = 0; j < 4; ++j) {
            const int d = d0 + j;
            const int swz2 = ((d >> 1) & 3) << 4;
            *(ushort*)(s0B + ((d * 64 + c * 2) ^ swz2)) = f2b(sp[j]);
        }
        const int dz = tid >> 2;
        const int off = 32 + (tid & 3) * 8;
        const int swzz = ((dz >> 1) & 3) << 4;
        *(uint2*)(s0B + ((dz * 64 + off) ^ swzz)) = make_uint2(0, 0);
    }
    if (tid < 16) e0s[tid] = ke_loc[(size_t)bid * C_ + tid];
    __syncthreads();

    // ---- two-level inclusive prefix of ke over t (+ e0) -> kesum_s ----
    {
        const int cc = tid & 15, g = tid >> 4;
        float s = 0.f;
        #pragma unroll
        for (int u = 0; u < 8; ++u) {
            const int t = g * 8 + u;
            s += b2f(*(const ushort*)(keB + ((t * 64 + cc * 2) ^ (((t >> 1) & 3) << 4))));
        }
        gsum[cc][g] = s;
    }
    __syncthreads();
    if (tid < 16) {
        float run = e0s[tid];
        #pragma unroll
        for (int g = 0; g < 16; ++g) { float tmp = gsum[tid][g]; gsum[tid][g] = run; run += tmp; }
    }
    __syncthreads();
    {
        const int cc = tid & 15, g = tid >> 4;
        float run = gsum[cc][g];
        #pragma unroll
        for (int u = 0; u < 8; ++u) {
            const int t = g * 8 + u;
            run += b2f(*(const ushort*)(keB + ((t * 64 + cc * 2) ^ (((t >> 1) & 3) << 4))));
            kesum_s[t][cc] = run;
        }
    }
    __syncthreads();

    // ---- qn = softmax(qc)*scale/(kesum+eps), bf16 (+ zero pad) ----
    if (tid < 128) {
        const int t = tid;
        const ushort* qrow = qkcv + (size_t)(b * T_ + t0 + t) * NW_ + h * C_;
        float qv[16];
        uint4 r0 = *(const uint4*)qrow, r1 = *(const uint4*)(qrow + 8);
        unpack8(r0, qv); unpack8(r1, qv + 8);
        float m = qv[0];
        #pragma unroll
        for (int c = 1; c < 16; ++c) m = fmaxf(m, qv[c]);
        float sum = 0.f;
        #pragma unroll
        for (int c = 0; c < 16; ++c) { qv[c] = __expf(qv[c] - m); sum += qv[c]; }
        const float inv = SCALE_ / sum;
        #pragma unroll
        for (int c = 0; c < 16; ++c) qv[c] = qv[c] * inv / (kesum_s[t][c] + 1e-9f);
        uint4 o0, o1;
        o0.x = pack2(qv[0], qv[1]);   o0.y = pack2(qv[2], qv[3]);
        o0.z = pack2(qv[4], qv[5]);   o0.w = pack2(qv[6], qv[7]);
        o1.x = pack2(qv[8], qv[9]);   o1.y = pack2(qv[10], qv[11]);
        o1.z = pack2(qv[12], qv[13]); o1.w = pack2(qv[14], qv[15]);
        const int swz = ((t >> 1) & 3) << 4;
        *(uint4*)(qnB + ((t * 64) ^ swz)) = o0;
        *(uint4*)(qnB + ((t * 64 + 16) ^ swz)) = o1;
        *(uint4*)(qnB + ((t * 64 + 32) ^ swz)) = make_uint4(0, 0, 0, 0);
        *(uint4*)(qnB + ((t * 64 + 48) ^ swz)) = make_uint4(0, 0, 0, 0);
    }
    __syncthreads();

    // ---- QK: P^T = Ke·Qn^T per 16x16 tile, mask, write Pl (bf16 swizzled) ----
    #pragma unroll
    for (int sr = 0; sr < 2; ++sr) {
        const int sb = wave * 2 + sr;
        const int s_row = sb * 16 + l15;
        short8 af = *(const short8*)(keB + ((s_row * 64 + lhi * 16) ^ (((s_row >> 1) & 3) << 4)));
        #pragma unroll
        for (int tb = 0; tb < 8; ++tb) {
            f32x4 p = (f32x4){0.f, 0.f, 0.f, 0.f};
            if (tb >= sb) {
                const int t_col = tb * 16 + l15;
                short8 bf = *(const short8*)(qnB + ((t_col * 64 + lhi * 16) ^ (((t_col >> 1) & 3) << 4)));
                p = __builtin_amdgcn_mfma_f32_16x16x32_bf16(af, bf, p, 0, 0, 0);
                if (tb == sb) {
                    #pragma unroll
                    for (int j = 0; j < 4; ++j)
                        p[j] = (lhi * 4 + j > l15) ? 0.f : p[j];
                }
            }
            const int t_g = tb * 16 + l15;
            const int sbase = sb * 16 + lhi * 4;
            const int swz = (t_g & 15) << 4;
            *(uint32_t*)(plB + ((t_g * 256 + sbase * 2) ^ swz)) = pack2(p[0], p[1]);
            *(uint32_t*)(plB + ((t_g * 256 + sbase * 2 + 4) ^ swz)) = pack2(p[2], p[3]);
        }
    }
    __syncthreads();

    // ---- O = Qn·S0 + P·V ----
    f32x4 acc[2][4];
    #pragma unroll
    for (int tt = 0; tt < 2; ++tt)
        #pragma unroll
        for (int dt = 0; dt < 4; ++dt) acc[tt][dt] = (f32x4){0.f, 0.f, 0.f, 0.f};

    const int trow = wave * 32;
    #pragma unroll
    for (int tt = 0; tt < 2; ++tt) {
        const int t_g = trow + tt * 16 + l15;
        short8 aq = *(const short8*)(qnB + ((t_g * 64 + lhi * 16) ^ (((t_g >> 1) & 3) << 4)));
        #pragma unroll
        for (int dt = 0; dt < 4; ++dt) {
            const int d = dt * 16 + l15;
            short8 bs = *(const short8*)(s0B + ((d * 64 + lhi * 16) ^ (((d >> 1) & 3) << 4)));
            acc[tt][dt] = __builtin_amdgcn_mfma_f32_16x16x32_bf16(aq, bs, acc[tt][dt], 0, 0, 0);
        }
        const int pswz = (t_g & 15) << 4;
        #pragma unroll
        for (int kb = 0; kb < 4; ++kb) {
            short8 ap = *(const short8*)(plB + ((t_g * 256 + kb * 64 + lhi * 16) ^ pswz));
            #pragma unroll
            for (int dt = 0; dt < 4; ++dt) {
                const int d = dt * 16 + l15;
                short8 bv = *(const short8*)(vtB + ((d * 256 + kb * 64 + lhi * 16) ^ ((d & 15) << 4)));
                acc[tt][dt] = __builtin_amdgcn_mfma_f32_16x16x32_bf16(ap, bv, acc[tt][dt], 0, 0, 0);
            }
        }
    }

    // ---- epilogue: C map col=l15(d), row=lhi*4+j (t) ----
    #pragma unroll
    for (int tt = 0; tt < 2; ++tt) {
        const int tg0 = t0 + trow + tt * 16 + lhi * 4;
        #pragma unroll
        for (int dt = 0; dt < 4; ++dt) {
            const int d = dt * 16 + l15;
            ushort* orow = xob + (size_t)(b * T_ + tg0) * D_ + h * HD_ + d;
            #pragma unroll
            for (int j = 0; j < 4; ++j)
                orow[(size_t)j * D_] = f2b(acc[tt][dt][j]);
        }
    }
}

// ---------------------------------------------------------------------------
extern "C" void kernel_launch(void* const* d_in, const int* in_sizes, int n_in,
                              void* d_out, int out_size, void* d_ws, size_t ws_size,
                              hipStream_t stream) {
    const float* x     = (const float*)d_in[0];   // (2,2048,1024)
    const float* w_qkv = (const float*)d_in[1];   // (3072,1024)
    const float* w_out = (const float*)d_in[2];   // (1024,1024)
    const float* code  = (const float*)d_in[3];   // (1,16,16,64)
    float* out = (float*)d_out;                   // (2,2048,1024)

    ushort* xb    = (ushort*)d_ws;                    // 4096*1024
    ushort* WallB = xb + (size_t)4096 * 1024;         // 1536*1024
    ushort* WoB   = WallB + (size_t)1536 * 1024;      // 1024*1024
    ushort* qkcv  = WoB + (size_t)1024 * 1024;        // 4096*1536
    ushort* xob   = qkcv + (size_t)4096 * 1536;       // 4096*1024
    ushort* vT    = xob + (size_t)4096 * 1024;        // 32*64*2048
    float*  ke_loc = (float*)(vT + (size_t)32 * 64 * 2048);  // 512*16
    float*  kv_loc = ke_loc + 512 * 16;               // 512*1024

    // casts + weight folding
    cast_bf16_kernel<<<2048, 256, 0, stream>>>(x, xb, 4096 * 1024);
    cast_bf16_kernel<<<512, 256, 0, stream>>>(w_qkv + (size_t)2048 * 1024,
                                              WallB + (size_t)512 * 1024, 1024 * 1024);
    cast_bf16_kernel<<<512, 256, 0, stream>>>(w_out, WoB, 1024 * 1024);
    fold_code_kernel<<<512, 256, 0, stream>>>(w_qkv, code, WallB);

    // fused qc|kc|v projection: (4096 x 1536 x 1024), bf16 out
    gemm_bf16_kernel<1><<<dim3(12, 32), 256, 0, stream>>>(xb, WallB, qkcv, 4096, NW_, 1024);

    // v transpose for intra MFMA B-operand
    vtrans_kernel<<<dim3(32, 16), 256, 0, stream>>>(qkcv, vT);

    // chunked linear attention
    chunk_local_kernel<<<512, 256, 0, stream>>>(qkcv, ke_loc, kv_loc);
    chunk_scan_kernel<<<32, 1024, 0, stream>>>(ke_loc, kv_loc);
    intra_kernel<<<512, 256, 0, stream>>>(qkcv, vT, ke_loc, kv_loc, xob);

    // out = xo @ w_out^T  (4096 x 1024 x 1024), fp32 out
    gemm_bf16_kernel<0><<<dim3(8, 32), 256, 0, stream>>>(xob, WoB, out, 4096, 1024, 1024);
}

// Round 4
// 93.599 us; speedup vs baseline: 6.4738x; 1.1058x over previous
//
#include <hip/hip_runtime.h>
#include <math.h>

// Problem constants (B=2, T=2048, D=1024, H=16, HD=64, C=16)
#define B_    2
#define T_    2048
#define D_    1024
#define H_    16
#define HD_   64
#define C_    16
#define SCALE_ 0.125f      // HEAD_DIM^-0.5
#define L_    128          // time-chunk length
#define NC_   16           // T_/L_
#define NW_   1536         // fused qc|kc|v width

typedef __attribute__((ext_vector_type(8))) short short8;
typedef __attribute__((ext_vector_type(4))) float f32x4;

__device__ inline float b2f(uint32_t u16) {
    return __uint_as_float(u16 << 16);
}
__device__ inline ushort f2b(float f) {   // RNE
    uint32_t u = __float_as_uint(f);
    return (ushort)((u + 0x7FFFu + ((u >> 16) & 1u)) >> 16);
}
__device__ inline uint32_t pack2(float a, float b) {
    return (uint32_t)f2b(a) | ((uint32_t)f2b(b) << 16);
}
__device__ inline void unpack2(uint32_t w, float& a, float& b) {
    a = b2f(w & 0xffffu); b = __uint_as_float(w & 0xffff0000u);
}
__device__ inline void unpack8(uint4 raw, float* dst) {
    unpack2(raw.x, dst[0], dst[1]);
    unpack2(raw.y, dst[2], dst[3]);
    unpack2(raw.z, dst[4], dst[5]);
    unpack2(raw.w, dst[6], dst[7]);
}
__device__ __forceinline__ void gll16(const ushort* g, ushort* l) {
    __builtin_amdgcn_global_load_lds(
        (const __attribute__((address_space(1))) void*)g,
        (__attribute__((address_space(3))) void*)l, 16, 0, 0);
}

// ---------------------------------------------------------------------------
// fp32 -> bf16 cast of x, 8 elems/thread
__global__ __launch_bounds__(256)
void cast_bf16_kernel(const float* __restrict__ in, ushort* __restrict__ out, int n) {
    int i = (blockIdx.x * 256 + threadIdx.x) * 8;
    if (i >= n) return;
    float4 a = *(const float4*)(in + i);
    float4 b = *(const float4*)(in + i + 4);
    uint4 o;
    o.x = pack2(a.x, a.y); o.y = pack2(a.z, a.w);
    o.z = pack2(b.x, b.y); o.w = pack2(b.z, b.w);
    *(uint4*)(out + i) = o;
}

// ---------------------------------------------------------------------------
// casts Wv (w_qkv rows 2048..3071) -> WallB[512..] and w_out -> WoB, one launch
__global__ __launch_bounds__(256)
void cast_w2_kernel(const float* __restrict__ w_qkv, const float* __restrict__ w_out,
                    ushort* __restrict__ WallB, ushort* __restrict__ WoB) {
    const int bid = blockIdx.x;          // 0..1023
    const int isW = bid >> 9;            // 0 => Wv, 1 => Wo
    const float* in = isW ? w_out : (w_qkv + (size_t)2048 * 1024);
    ushort* out = isW ? WoB : (WallB + (size_t)512 * 1024);
    const int i = (bid & 511) * 2048 + threadIdx.x * 8;
    float4 a = *(const float4*)(in + i);
    float4 b = *(const float4*)(in + i + 4);
    uint4 o;
    o.x = pack2(a.x, a.y); o.y = pack2(a.z, a.w);
    o.z = pack2(b.x, b.y); o.w = pack2(b.z, b.w);
    *(uint4*)(out + i) = o;
}

// ---------------------------------------------------------------------------
// Fold fc_code into the q/k slices of w_qkv, write bf16 rows 0..511 of W_all
__global__ __launch_bounds__(256)
void fold_code_kernel(const float* __restrict__ w_qkv, const float* __restrict__ code,
                      ushort* __restrict__ WallB) {
    const int bid = blockIdx.x;      // 0..511
    const int isK = bid >> 8;
    const int row = bid & 255;       // h*16+c
    const int h = row >> 4;
    __shared__ float cs[HD_];
    if (threadIdx.x < HD_) cs[threadIdx.x] = code[row * HD_ + threadIdx.x];
    __syncthreads();
    const float* wbase = w_qkv + (size_t)(isK * D_ + h * HD_) * D_;
    ushort* outp = WallB + (size_t)(isK * 256 + row) * D_;
    for (int e = threadIdx.x; e < D_; e += 256) {
        float acc = 0.f;
        #pragma unroll 8
        for (int d = 0; d < HD_; ++d) acc += wbase[(size_t)d * D_ + e] * cs[d];
        outp[e] = f2b(acc * SCALE_);
    }
}

// ---------------------------------------------------------------------------
// bf16 MFMA GEMM: C[M,N] = A[M,K] @ B[N,K]^T. 128x128 tile, BK=64, 4 waves.
// 2-phase double-buffered pipeline (T3 minimum recipe): STAGE(next) issued
// before compute(cur); single __syncthreads per K-step (its vmcnt(0) drain is
// the "next tile ready" wait). XCD-aware block swizzle (T1, bijective since
// nwg % 8 == 0 for our launches).
template<int WRITE_BF16>
__global__ __launch_bounds__(256)
void gemm_bf16_kernel(const ushort* __restrict__ A, const ushort* __restrict__ Bw,
                      void* __restrict__ Cv, int M, int N, int K) {
    __shared__ ushort As[2][128 * 64];   // 2 x 16 KB
    __shared__ ushort Bs[2][128 * 64];   // 2 x 16 KB
    const int tid  = threadIdx.x;
    const int wave = tid >> 6;
    const int lane = tid & 63;
    const int wr = wave >> 1, wc = wave & 1;

    // XCD swizzle: contiguous tile chunk per XCD
    const int gx = gridDim.x;
    int f = blockIdx.y * gx + blockIdx.x;
    const int nwg = gx * gridDim.y;
    if ((nwg & 7) == 0) f = (f & 7) * (nwg >> 3) + (f >> 3);
    const int row0 = (f / gx) * 128;
    const int col0 = (f % gx) * 128;

    f32x4 acc[4][4];
    #pragma unroll
    for (int m = 0; m < 4; ++m)
        #pragma unroll
        for (int n = 0; n < 4; ++n) acc[m][n] = (f32x4){0.f, 0.f, 0.f, 0.f};

    // staging constants: linear LDS dest, pre-swizzled global source
    const int srow = lane >> 3;
    const int kA   = ((lane & 7) ^ srow) << 3;
    // fragment-read constants
    const int lane15 = lane & 15;
    const int lhi    = lane >> 4;
    const int axor   = (lane15 & 7) << 4;

    const int NT = K >> 6;

    // prologue: stage tile 0 into buf 0
    #pragma unroll
    for (int i = 0; i < 4; ++i) {
        const int seg = wave * 4 + i;
        const int r = seg * 8 + srow;
        gll16(A  + (size_t)(row0 + r) * K + kA, &As[0][seg * 512]);
        gll16(Bw + (size_t)(col0 + r) * K + kA, &Bs[0][seg * 512]);
    }
    __syncthreads();

    for (int it = 0; it < NT; ++it) {
        const int cur = it & 1;
        if (it + 1 < NT) {   // prefetch next tile into other buffer
            const int kk = (it + 1) << 6;
            #pragma unroll
            for (int i = 0; i < 4; ++i) {
                const int seg = wave * 4 + i;
                const int r = seg * 8 + srow;
                gll16(A  + (size_t)(row0 + r) * K + kk + kA, &As[cur ^ 1][seg * 512]);
                gll16(Bw + (size_t)(col0 + r) * K + kk + kA, &Bs[cur ^ 1][seg * 512]);
            }
        }
        const char* Ab = (const char*)As[cur];
        const char* Bb = (const char*)Bs[cur];
        #pragma unroll
        for (int s = 0; s < 2; ++s) {
            short8 af[4], bf[4];
            #pragma unroll
            for (int m = 0; m < 4; ++m) {
                const int r = wr * 64 + m * 16 + lane15;
                const int off = (r * 128 + s * 64 + lhi * 16) ^ axor;
                af[m] = *(const short8*)(Ab + off);
            }
            #pragma unroll
            for (int n = 0; n < 4; ++n) {
                const int r = wc * 64 + n * 16 + lane15;
                const int off = (r * 128 + s * 64 + lhi * 16) ^ axor;
                bf[n] = *(const short8*)(Bb + off);
            }
            #pragma unroll
            for (int m = 0; m < 4; ++m)
                #pragma unroll
                for (int n = 0; n < 4; ++n)
                    acc[m][n] = __builtin_amdgcn_mfma_f32_16x16x32_bf16(
                        af[m], bf[n], acc[m][n], 0, 0, 0);
        }
        __syncthreads();   // drains prefetch (vmcnt 0) + protects buffers
    }

    #pragma unroll
    for (int m = 0; m < 4; ++m) {
        #pragma unroll
        for (int n = 0; n < 4; ++n) {
            const int row = row0 + wr * 64 + m * 16 + lhi * 4;
            const int col = col0 + wc * 64 + n * 16 + lane15;
            if (WRITE_BF16) {
                ushort* C = (ushort*)Cv;
                #pragma unroll
                for (int j = 0; j < 4; ++j)
                    C[(size_t)(row + j) * N + col] = f2b(acc[m][n][j]);
            } else {
                float* C = (float*)Cv;
                #pragma unroll
                for (int j = 0; j < 4; ++j)
                    C[(size_t)(row + j) * N + col] = acc[m][n][j];
            }
        }
    }
}

// ---------------------------------------------------------------------------
// Fused vtrans + chunk_local. Per (b,h,chunk):
//  - stage v tile [128t][64d] (bf16, swizzled) once
//  - write transposed vT[bh][d][t]
//  - ke_loc[c] = sum_t exp(kc[t,c]); kv_loc[c,d] = sum_t exp(kc[t,c])*v[t,d]
__global__ __launch_bounds__(256)
void prep_attn_kernel(const ushort* __restrict__ qkcv, ushort* __restrict__ vT,
                      float* __restrict__ ke_loc, float* __restrict__ kv_loc) {
    const int bid = blockIdx.x;            // bh*NC_ + chunk
    const int chunk = bid & (NC_ - 1);
    const int bh = bid >> 4;
    const int b = bh >> 4, h = bh & 15;
    const int t0 = chunk * L_;
    const int tid = threadIdx.x;
    __shared__ __align__(16) ushort tile[128 * 64];   // 16 KB, swz ((t>>3)&7)<<4
    __shared__ float ke_s[L_][C_];                    // 8 KB
    __shared__ float gsum[C_][16];
    char* tB = (char*)tile;

    // stage v tile (swizzled) from qkcv
    #pragma unroll
    for (int r = 0; r < 4; ++r) {
        const int idx = r * 2048 + tid * 8;
        const int t = idx >> 6, d0 = idx & 63;
        uint4 raw = *(const uint4*)(qkcv + (size_t)(b * T_ + t0 + t) * NW_ + 512 + h * 64 + d0);
        *(uint4*)(tB + ((t * 128 + d0 * 2) ^ (((t >> 3) & 7) << 4))) = raw;
    }
    // stage ke = exp(kc), fp32
    {
        const int t = tid >> 1, c0 = (tid & 1) * 8;
        uint4 raw = *(const uint4*)(qkcv + (size_t)(b * T_ + t0 + t) * NW_ + 256 + h * C_ + c0);
        float f[8]; unpack8(raw, f);
        #pragma unroll
        for (int j = 0; j < 8; ++j) ke_s[t][c0 + j] = __expf(f[j]);
    }
    __syncthreads();

    // write transposed vT
    {
        const int d = tid >> 2, tq = tid & 3;
        ushort* obase = vT + ((size_t)bh * 64 + d) * 2048 + t0;
        #pragma unroll
        for (int c8 = 0; c8 < 4; ++c8) {
            const int tA = c8 * 32 + tq * 8;
            uint32_t w[4];
            #pragma unroll
            for (int p = 0; p < 4; ++p) {
                const int tL = tA + p * 2;
                uint32_t lo = *(const ushort*)(tB + ((tL * 128 + d * 2) ^ (((tL >> 3) & 7) << 4)));
                uint32_t hi = *(const ushort*)(tB + (((tL + 1) * 128 + d * 2) ^ ((((tL + 1) >> 3) & 7) << 4)));
                w[p] = lo | (hi << 16);
            }
            uint4 o; o.x = w[0]; o.y = w[1]; o.z = w[2]; o.w = w[3];
            *(uint4*)(obase + tA) = o;
        }
    }

    // kv_loc accumulation
    const int c = tid >> 4;
    const int dg = (tid & 15) << 2;
    float a0 = 0.f, a1 = 0.f, a2 = 0.f, a3 = 0.f;
    for (int t = 0; t < L_; ++t) {
        const float kev = ke_s[t][c];
        uint2 rv = *(const uint2*)(tB + ((t * 128 + dg * 2) ^ (((t >> 3) & 7) << 4)));
        float v0, v1, v2, v3;
        unpack2(rv.x, v0, v1); unpack2(rv.y, v2, v3);
        a0 += kev * v0; a1 += kev * v1; a2 += kev * v2; a3 += kev * v3;
    }
    {   // two-level ke column sums
        const int cc = tid & 15, g = tid >> 4;
        float s = 0.f;
        #pragma unroll
        for (int u = 0; u < 8; ++u) s += ke_s[g * 8 + u][cc];
        gsum[cc][g] = s;
    }
    __syncthreads();
    if (tid < C_) {
        float s = 0.f;
        #pragma unroll
        for (int g = 0; g < 16; ++g) s += gsum[tid][g];
        ke_loc[(size_t)bid * C_ + tid] = s;
    }
    *(float4*)(kv_loc + (size_t)bid * 1024 + c * HD_ + dg) = make_float4(a0, a1, a2, a3);
}

// ---------------------------------------------------------------------------
// In-place exclusive prefix over the NC_ chunks, per (b,h). 32 blocks.
__global__ __launch_bounds__(1024)
void chunk_scan_kernel(float* __restrict__ ke_loc, float* __restrict__ kv_loc) {
    const int bh = blockIdx.x;
    const int tid = threadIdx.x;
    float run = 0.f;
    for (int ch = 0; ch < NC_; ++ch) {
        size_t idx = ((size_t)(bh * NC_ + ch)) * 1024 + tid;
        float tmp = kv_loc[idx];
        kv_loc[idx] = run;
        run += tmp;
    }
    if (tid < C_) {
        float run2 = 0.f;
        for (int ch = 0; ch < NC_; ++ch) {
            size_t idx = ((size_t)(bh * NC_ + ch)) * C_ + tid;
            float tmp = ke_loc[idx];
            ke_loc[idx] = run2;
            run2 += tmp;
        }
    }
}

// ---------------------------------------------------------------------------
// MFMA intra: per (b,h,chunk):
//   P^T = Ke·Qn^T (16x16x32, K zero-padded), causal mask, P -> swizzled LDS bf16
//   O = Qn·S0 + P·V  (V from pre-transposed vT)
__global__ __launch_bounds__(256)
void intra_kernel(const ushort* __restrict__ qkcv, const ushort* __restrict__ vT,
                  const float* __restrict__ ke_loc, const float* __restrict__ kv_loc,
                  ushort* __restrict__ xob) {
    const int bid = blockIdx.x;
    const int chunk = bid & (NC_ - 1);
    const int bh = bid >> 4;
    const int b = bh >> 4, h = bh & 15;
    const int t0 = chunk * L_;
    const int tid = threadIdx.x;
    const int wave = tid >> 6, lane = tid & 63;
    const int l15 = lane & 15, lhi = lane >> 4;

    __shared__ __align__(16) ushort ke_bf[128 * 32];
    __shared__ __align__(16) ushort qn_bf[128 * 32];
    __shared__ __align__(16) ushort Vt_s[64 * 128];
    __shared__ __align__(16) ushort Pl[128 * 128];
    __shared__ __align__(16) ushort S0t[64 * 32];
    __shared__ float kesum_s[128][16];
    __shared__ float gsum[16][16];
    __shared__ float e0s[16];

    char* keB = (char*)ke_bf;
    char* qnB = (char*)qn_bf;
    char* vtB = (char*)Vt_s;
    char* plB = (char*)Pl;
    char* s0B = (char*)S0t;

    // ---- stage ke = exp(kc) as bf16 (+ zero pad) ----
    {
        const int t = tid >> 1, c0 = (tid & 1) * 8;
        uint4 raw = *(const uint4*)(qkcv + (size_t)(b * T_ + t0 + t) * NW_ + 256 + h * C_ + c0);
        float f[8]; unpack8(raw, f);
        uint4 o;
        o.x = pack2(__expf(f[0]), __expf(f[1]));
        o.y = pack2(__expf(f[2]), __expf(f[3]));
        o.z = pack2(__expf(f[4]), __expf(f[5]));
        o.w = pack2(__expf(f[6]), __expf(f[7]));
        const int swz = ((t >> 1) & 3) << 4;
        *(uint4*)(keB + ((t * 64 + c0 * 2) ^ swz)) = o;
        *(uint4*)(keB + ((t * 64 + 32 + c0 * 2) ^ swz)) = make_uint4(0, 0, 0, 0);
    }
    // ---- stage Vt (bf16 [d][s] swizzled) from vT global ----
    {
        const int d = tid >> 2, q = tid & 3;
        const ushort* src = vT + ((size_t)bh * 64 + d) * 2048 + t0 + q * 32;
        const int swz = (d & 15) << 4;
        #pragma unroll
        for (int i = 0; i < 4; ++i) {
            uint4 raw = *(const uint4*)(src + i * 8);
            *(uint4*)(vtB + ((d * 256 + q * 64 + i * 16) ^ swz)) = raw;
        }
    }
    // ---- stage S0t = kv_loc^T (bf16 padded) + zero pad + e0 ----
    {
        const int c = tid >> 4;
        const int d0 = (tid & 15) * 4;
        float4 s4 = *(const float4*)(kv_loc + (size_t)bid * 1024 + c * 64 + d0);
        const float* sp = (const float*)&s4;
        #pragma unroll
        for (int j = 0; j < 4; ++j) {
            const int d = d0 + j;
            const int swz2 = ((d >> 1) & 3) << 4;
            *(ushort*)(s0B + ((d * 64 + c * 2) ^ swz2)) = f2b(sp[j]);
        }
        const int dz = tid >> 2;
        const int off = 32 + (tid & 3) * 8;
        const int swzz = ((dz >> 1) & 3) << 4;
        *(uint2*)(s0B + ((dz * 64 + off) ^ swzz)) = make_uint2(0, 0);
    }
    if (tid < 16) e0s[tid] = ke_loc[(size_t)bid * C_ + tid];
    __syncthreads();

    // ---- two-level inclusive prefix of ke over t (+ e0) -> kesum_s ----
    {
        const int cc = tid & 15, g = tid >> 4;
        float s = 0.f;
        #pragma unroll
        for (int u = 0; u < 8; ++u) {
            const int t = g * 8 + u;
            s += b2f(*(const ushort*)(keB + ((t * 64 + cc * 2) ^ (((t >> 1) & 3) << 4))));
        }
        gsum[cc][g] = s;
    }
    __syncthreads();
    if (tid < 16) {
        float run = e0s[tid];
        #pragma unroll
        for (int g = 0; g < 16; ++g) { float tmp = gsum[tid][g]; gsum[tid][g] = run; run += tmp; }
    }
    __syncthreads();
    {
        const int cc = tid & 15, g = tid >> 4;
        float run = gsum[cc][g];
        #pragma unroll
        for (int u = 0; u < 8; ++u) {
            const int t = g * 8 + u;
            run += b2f(*(const ushort*)(keB + ((t * 64 + cc * 2) ^ (((t >> 1) & 3) << 4))));
            kesum_s[t][cc] = run;
        }
    }
    __syncthreads();

    // ---- qn = softmax(qc)*scale/(kesum+eps), bf16 (+ zero pad) ----
    if (tid < 128) {
        const int t = tid;
        const ushort* qrow = qkcv + (size_t)(b * T_ + t0 + t) * NW_ + h * C_;
        float qv[16];
        uint4 r0 = *(const uint4*)qrow, r1 = *(const uint4*)(qrow + 8);
        unpack8(r0, qv); unpack8(r1, qv + 8);
        float m = qv[0];
        #pragma unroll
        for (int c = 1; c < 16; ++c) m = fmaxf(m, qv[c]);
        float sum = 0.f;
        #pragma unroll
        for (int c = 0; c < 16; ++c) { qv[c] = __expf(qv[c] - m); sum += qv[c]; }
        const float inv = SCALE_ / sum;
        #pragma unroll
        for (int c = 0; c < 16; ++c) qv[c] = qv[c] * inv / (kesum_s[t][c] + 1e-9f);
        uint4 o0, o1;
        o0.x = pack2(qv[0], qv[1]);   o0.y = pack2(qv[2], qv[3]);
        o0.z = pack2(qv[4], qv[5]);   o0.w = pack2(qv[6], qv[7]);
        o1.x = pack2(qv[8], qv[9]);   o1.y = pack2(qv[10], qv[11]);
        o1.z = pack2(qv[12], qv[13]); o1.w = pack2(qv[14], qv[15]);
        const int swz = ((t >> 1) & 3) << 4;
        *(uint4*)(qnB + ((t * 64) ^ swz)) = o0;
        *(uint4*)(qnB + ((t * 64 + 16) ^ swz)) = o1;
        *(uint4*)(qnB + ((t * 64 + 32) ^ swz)) = make_uint4(0, 0, 0, 0);
        *(uint4*)(qnB + ((t * 64 + 48) ^ swz)) = make_uint4(0, 0, 0, 0);
    }
    __syncthreads();

    // ---- QK: P^T = Ke·Qn^T per 16x16 tile, mask, write Pl (bf16 swizzled) ----
    #pragma unroll
    for (int sr = 0; sr < 2; ++sr) {
        const int sb = wave * 2 + sr;
        const int s_row = sb * 16 + l15;
        short8 af = *(const short8*)(keB + ((s_row * 64 + lhi * 16) ^ (((s_row >> 1) & 3) << 4)));
        #pragma unroll
        for (int tb = 0; tb < 8; ++tb) {
            f32x4 p = (f32x4){0.f, 0.f, 0.f, 0.f};
            if (tb >= sb) {
                const int t_col = tb * 16 + l15;
                short8 bf = *(const short8*)(qnB + ((t_col * 64 + lhi * 16) ^ (((t_col >> 1) & 3) << 4)));
                p = __builtin_amdgcn_mfma_f32_16x16x32_bf16(af, bf, p, 0, 0, 0);
                if (tb == sb) {
                    #pragma unroll
                    for (int j = 0; j < 4; ++j)
                        p[j] = (lhi * 4 + j > l15) ? 0.f : p[j];
                }
            }
            const int t_g = tb * 16 + l15;
            const int sbase = sb * 16 + lhi * 4;
            const int swz = (t_g & 15) << 4;
            *(uint32_t*)(plB + ((t_g * 256 + sbase * 2) ^ swz)) = pack2(p[0], p[1]);
            *(uint32_t*)(plB + ((t_g * 256 + sbase * 2 + 4) ^ swz)) = pack2(p[2], p[3]);
        }
    }
    __syncthreads();

    // ---- O = Qn·S0 + P·V ----
    f32x4 acc[2][4];
    #pragma unroll
    for (int tt = 0; tt < 2; ++tt)
        #pragma unroll
        for (int dt = 0; dt < 4; ++dt) acc[tt][dt] = (f32x4){0.f, 0.f, 0.f, 0.f};

    const int trow = wave * 32;
    #pragma unroll
    for (int tt = 0; tt < 2; ++tt) {
        const int t_g = trow + tt * 16 + l15;
        short8 aq = *(const short8*)(qnB + ((t_g * 64 + lhi * 16) ^ (((t_g >> 1) & 3) << 4)));
        #pragma unroll
        for (int dt = 0; dt < 4; ++dt) {
            const int d = dt * 16 + l15;
            short8 bs = *(const short8*)(s0B + ((d * 64 + lhi * 16) ^ (((d >> 1) & 3) << 4)));
            acc[tt][dt] = __builtin_amdgcn_mfma_f32_16x16x32_bf16(aq, bs, acc[tt][dt], 0, 0, 0);
        }
        const int pswz = (t_g & 15) << 4;
        #pragma unroll
        for (int kb = 0; kb < 4; ++kb) {
            short8 ap = *(const short8*)(plB + ((t_g * 256 + kb * 64 + lhi * 16) ^ pswz));
            #pragma unroll
            for (int dt = 0; dt < 4; ++dt) {
                const int d = dt * 16 + l15;
                short8 bv = *(const short8*)(vtB + ((d * 256 + kb * 64 + lhi * 16) ^ ((d & 15) << 4)));
                acc[tt][dt] = __builtin_amdgcn_mfma_f32_16x16x32_bf16(ap, bv, acc[tt][dt], 0, 0, 0);
            }
        }
    }

    // ---- epilogue ----
    #pragma unroll
    for (int tt = 0; tt < 2; ++tt) {
        const int tg0 = t0 + trow + tt * 16 + lhi * 4;
        #pragma unroll
        for (int dt = 0; dt < 4; ++dt) {
            const int d = dt * 16 + l15;
            ushort* orow = xob + (size_t)(b * T_ + tg0) * D_ + h * HD_ + d;
            #pragma unroll
            for (int j = 0; j < 4; ++j)
                orow[(size_t)j * D_] = f2b(acc[tt][dt][j]);
        }
    }
}

// ---------------------------------------------------------------------------
extern "C" void kernel_launch(void* const* d_in, const int* in_sizes, int n_in,
                              void* d_out, int out_size, void* d_ws, size_t ws_size,
                              hipStream_t stream) {
    const float* x     = (const float*)d_in[0];   // (2,2048,1024)
    const float* w_qkv = (const float*)d_in[1];   // (3072,1024)
    const float* w_out = (const float*)d_in[2];   // (1024,1024)
    const float* code  = (const float*)d_in[3];   // (1,16,16,64)
    float* out = (float*)d_out;                   // (2,2048,1024)

    ushort* xb    = (ushort*)d_ws;                    // 4096*1024
    ushort* WallB = xb + (size_t)4096 * 1024;         // 1536*1024
    ushort* WoB   = WallB + (size_t)1536 * 1024;      // 1024*1024
    ushort* qkcv  = WoB + (size_t)1024 * 1024;        // 4096*1536
    ushort* xob   = qkcv + (size_t)4096 * 1536;       // 4096*1024
    ushort* vT    = xob + (size_t)4096 * 1024;        // 32*64*2048
    float*  ke_loc = (float*)(vT + (size_t)32 * 64 * 2048);  // 512*16
    float*  kv_loc = ke_loc + 512 * 16;               // 512*1024

    // casts + weight folding
    cast_bf16_kernel<<<2048, 256, 0, stream>>>(x, xb, 4096 * 1024);
    cast_w2_kernel<<<1024, 256, 0, stream>>>(w_qkv, w_out, WallB, WoB);
    fold_code_kernel<<<512, 256, 0, stream>>>(w_qkv, code, WallB);

    // fused qc|kc|v projection: (4096 x 1536 x 1024), bf16 out
    gemm_bf16_kernel<1><<<dim3(12, 32), 256, 0, stream>>>(xb, WallB, qkcv, 4096, NW_, 1024);

    // fused v-transpose + chunk-local sums
    prep_attn_kernel<<<512, 256, 0, stream>>>(qkcv, vT, ke_loc, kv_loc);
    chunk_scan_kernel<<<32, 1024, 0, stream>>>(ke_loc, kv_loc);
    intra_kernel<<<512, 256, 0, stream>>>(qkcv, vT, ke_loc, kv_loc, xob);

    // out = xo @ w_out^T  (4096 x 1024 x 1024), fp32 out
    gemm_bf16_kernel<0><<<dim3(8, 32), 256, 0, stream>>>(xob, WoB, out, 4096, 1024, 1024);
}

// Round 5
// 90.668 us; speedup vs baseline: 6.6830x; 1.0323x over previous
//
#include <hip/hip_runtime.h>
#include <math.h>

// Problem constants (B=2, T=2048, D=1024, H=16, HD=64, C=16)
#define B_    2
#define T_    2048
#define D_    1024
#define H_    16
#define HD_   64
#define C_    16
#define SCALE_ 0.125f      // HEAD_DIM^-0.5
#define L_    128          // time-chunk length
#define NC_   16           // T_/L_
#define NW_   1536         // fused qc|kc|v width

typedef __attribute__((ext_vector_type(8))) short short8;
typedef __attribute__((ext_vector_type(4))) float f32x4;

__device__ inline float b2f(uint32_t u16) {
    return __uint_as_float(u16 << 16);
}
__device__ inline ushort f2b(float f) {   // RNE
    uint32_t u = __float_as_uint(f);
    return (ushort)((u + 0x7FFFu + ((u >> 16) & 1u)) >> 16);
}
__device__ inline uint32_t pack2(float a, float b) {
    return (uint32_t)f2b(a) | ((uint32_t)f2b(b) << 16);
}
__device__ inline void unpack2(uint32_t w, float& a, float& b) {
    a = b2f(w & 0xffffu); b = __uint_as_float(w & 0xffff0000u);
}
__device__ inline void unpack8(uint4 raw, float* dst) {
    unpack2(raw.x, dst[0], dst[1]);
    unpack2(raw.y, dst[2], dst[3]);
    unpack2(raw.z, dst[4], dst[5]);
    unpack2(raw.w, dst[6], dst[7]);
}
__device__ __forceinline__ void gll16(const ushort* g, ushort* l) {
    __builtin_amdgcn_global_load_lds(
        (const __attribute__((address_space(1))) void*)g,
        (__attribute__((address_space(3))) void*)l, 16, 0, 0);
}

// ---------------------------------------------------------------------------
// Merged input prep: blockIdx ranges
//   [0,2048)    : cast x fp32 -> bf16 (2048 elems/block)
//   [2048,3072) : cast Wv / w_out -> bf16
//   [3072,3584) : fold fc_code into q/k slices -> WallB rows 0..511
__global__ __launch_bounds__(256)
void prep_inputs_kernel(const float* __restrict__ x, const float* __restrict__ w_qkv,
                        const float* __restrict__ w_out, const float* __restrict__ code,
                        ushort* __restrict__ xb, ushort* __restrict__ WallB,
                        ushort* __restrict__ WoB) {
    const int bid = blockIdx.x;
    if (bid < 3072) {
        const float* in;
        ushort* out;
        int i;
        if (bid < 2048) {
            in = x; out = xb;
            i = bid * 2048 + threadIdx.x * 8;
        } else {
            const int sub = bid - 2048;
            const int isW = sub >> 9;
            in = isW ? w_out : (w_qkv + (size_t)2048 * 1024);
            out = isW ? WoB : (WallB + (size_t)512 * 1024);
            i = (sub & 511) * 2048 + threadIdx.x * 8;
        }
        float4 a = *(const float4*)(in + i);
        float4 b = *(const float4*)(in + i + 4);
        uint4 o;
        o.x = pack2(a.x, a.y); o.y = pack2(a.z, a.w);
        o.z = pack2(b.x, b.y); o.w = pack2(b.z, b.w);
        *(uint4*)(out + i) = o;
    } else {
        const int sub = bid - 3072;      // 0..511
        const int isK = sub >> 8;
        const int row = sub & 255;       // h*16+c
        const int h = row >> 4;
        __shared__ float cs[HD_];
        if (threadIdx.x < HD_) cs[threadIdx.x] = code[row * HD_ + threadIdx.x];
        __syncthreads();
        const float* wbase = w_qkv + (size_t)(isK * D_ + h * HD_) * D_;
        ushort* outp = WallB + (size_t)(isK * 256 + row) * D_;
        for (int e = threadIdx.x; e < D_; e += 256) {
            float acc = 0.f;
            #pragma unroll 8
            for (int d = 0; d < HD_; ++d) acc += wbase[(size_t)d * D_ + e] * cs[d];
            outp[e] = f2b(acc * SCALE_);
        }
    }
}

// ---------------------------------------------------------------------------
// bf16 MFMA GEMM: C[M,N] = A[M,K] @ B[N,K]^T. 128x128 tile, BK=64, 4 waves.
// 2-phase double-buffered pipeline; XCD-aware block swizzle (bijective since
// nwg % 8 == 0 for our launches).
template<int WRITE_BF16>
__global__ __launch_bounds__(256)
void gemm_bf16_kernel(const ushort* __restrict__ A, const ushort* __restrict__ Bw,
                      void* __restrict__ Cv, int M, int N, int K) {
    __shared__ ushort As[2][128 * 64];   // 2 x 16 KB
    __shared__ ushort Bs[2][128 * 64];   // 2 x 16 KB
    const int tid  = threadIdx.x;
    const int wave = tid >> 6;
    const int lane = tid & 63;
    const int wr = wave >> 1, wc = wave & 1;

    // XCD swizzle: contiguous tile chunk per XCD
    const int gx = gridDim.x;
    int f = blockIdx.y * gx + blockIdx.x;
    const int nwg = gx * gridDim.y;
    if ((nwg & 7) == 0) f = (f & 7) * (nwg >> 3) + (f >> 3);
    const int row0 = (f / gx) * 128;
    const int col0 = (f % gx) * 128;

    f32x4 acc[4][4];
    #pragma unroll
    for (int m = 0; m < 4; ++m)
        #pragma unroll
        for (int n = 0; n < 4; ++n) acc[m][n] = (f32x4){0.f, 0.f, 0.f, 0.f};

    // staging constants: linear LDS dest, pre-swizzled global source
    const int srow = lane >> 3;
    const int kA   = ((lane & 7) ^ srow) << 3;
    // fragment-read constants
    const int lane15 = lane & 15;
    const int lhi    = lane >> 4;
    const int axor   = (lane15 & 7) << 4;

    const int NT = K >> 6;

    // prologue: stage tile 0 into buf 0
    #pragma unroll
    for (int i = 0; i < 4; ++i) {
        const int seg = wave * 4 + i;
        const int r = seg * 8 + srow;
        gll16(A  + (size_t)(row0 + r) * K + kA, &As[0][seg * 512]);
        gll16(Bw + (size_t)(col0 + r) * K + kA, &Bs[0][seg * 512]);
    }
    __syncthreads();

    for (int it = 0; it < NT; ++it) {
        const int cur = it & 1;
        if (it + 1 < NT) {   // prefetch next tile into other buffer
            const int kk = (it + 1) << 6;
            #pragma unroll
            for (int i = 0; i < 4; ++i) {
                const int seg = wave * 4 + i;
                const int r = seg * 8 + srow;
                gll16(A  + (size_t)(row0 + r) * K + kk + kA, &As[cur ^ 1][seg * 512]);
                gll16(Bw + (size_t)(col0 + r) * K + kk + kA, &Bs[cur ^ 1][seg * 512]);
            }
        }
        const char* Ab = (const char*)As[cur];
        const char* Bb = (const char*)Bs[cur];
        #pragma unroll
        for (int s = 0; s < 2; ++s) {
            short8 af[4], bf[4];
            #pragma unroll
            for (int m = 0; m < 4; ++m) {
                const int r = wr * 64 + m * 16 + lane15;
                const int off = (r * 128 + s * 64 + lhi * 16) ^ axor;
                af[m] = *(const short8*)(Ab + off);
            }
            #pragma unroll
            for (int n = 0; n < 4; ++n) {
                const int r = wc * 64 + n * 16 + lane15;
                const int off = (r * 128 + s * 64 + lhi * 16) ^ axor;
                bf[n] = *(const short8*)(Bb + off);
            }
            #pragma unroll
            for (int m = 0; m < 4; ++m)
                #pragma unroll
                for (int n = 0; n < 4; ++n)
                    acc[m][n] = __builtin_amdgcn_mfma_f32_16x16x32_bf16(
                        af[m], bf[n], acc[m][n], 0, 0, 0);
        }
        __syncthreads();   // drains prefetch (vmcnt 0) + protects buffers
    }

    #pragma unroll
    for (int m = 0; m < 4; ++m) {
        #pragma unroll
        for (int n = 0; n < 4; ++n) {
            const int row = row0 + wr * 64 + m * 16 + lhi * 4;
            const int col = col0 + wc * 64 + n * 16 + lane15;
            if (WRITE_BF16) {
                ushort* C = (ushort*)Cv;
                #pragma unroll
                for (int j = 0; j < 4; ++j)
                    C[(size_t)(row + j) * N + col] = f2b(acc[m][n][j]);
            } else {
                float* C = (float*)Cv;
                #pragma unroll
                for (int j = 0; j < 4; ++j)
                    C[(size_t)(row + j) * N + col] = acc[m][n][j];
            }
        }
    }
}

// ---------------------------------------------------------------------------
// Fused vtrans + chunk-local sums. Per (b,h,chunk):
//  - stage v tile [128t][64d] (bf16, swizzled) once
//  - write transposed vT[bh][d][t]
//  - ke_loc[c] = sum_t exp(kc[t,c]); kv_loc[c,d] = sum_t exp(kc[t,c])*v[t,d]
// (LOCAL sums only — prefix over chunks is folded into intra_kernel.)
__global__ __launch_bounds__(256)
void prep_attn_kernel(const ushort* __restrict__ qkcv, ushort* __restrict__ vT,
                      float* __restrict__ ke_loc, float* __restrict__ kv_loc) {
    const int bid = blockIdx.x;            // bh*NC_ + chunk
    const int chunk = bid & (NC_ - 1);
    const int bh = bid >> 4;
    const int b = bh >> 4, h = bh & 15;
    const int t0 = chunk * L_;
    const int tid = threadIdx.x;
    __shared__ __align__(16) ushort tile[128 * 64];   // 16 KB, swz ((t>>3)&7)<<4
    __shared__ float ke_s[L_][C_];                    // 8 KB
    __shared__ float gsum[C_][16];
    char* tB = (char*)tile;

    // stage v tile (swizzled) from qkcv
    #pragma unroll
    for (int r = 0; r < 4; ++r) {
        const int idx = r * 2048 + tid * 8;
        const int t = idx >> 6, d0 = idx & 63;
        uint4 raw = *(const uint4*)(qkcv + (size_t)(b * T_ + t0 + t) * NW_ + 512 + h * 64 + d0);
        *(uint4*)(tB + ((t * 128 + d0 * 2) ^ (((t >> 3) & 7) << 4))) = raw;
    }
    // stage ke = exp(kc), fp32
    {
        const int t = tid >> 1, c0 = (tid & 1) * 8;
        uint4 raw = *(const uint4*)(qkcv + (size_t)(b * T_ + t0 + t) * NW_ + 256 + h * C_ + c0);
        float f[8]; unpack8(raw, f);
        #pragma unroll
        for (int j = 0; j < 8; ++j) ke_s[t][c0 + j] = __expf(f[j]);
    }
    __syncthreads();

    // write transposed vT
    {
        const int d = tid >> 2, tq = tid & 3;
        ushort* obase = vT + ((size_t)bh * 64 + d) * 2048 + t0;
        #pragma unroll
        for (int c8 = 0; c8 < 4; ++c8) {
            const int tA = c8 * 32 + tq * 8;
            uint32_t w[4];
            #pragma unroll
            for (int p = 0; p < 4; ++p) {
                const int tL = tA + p * 2;
                uint32_t lo = *(const ushort*)(tB + ((tL * 128 + d * 2) ^ (((tL >> 3) & 7) << 4)));
                uint32_t hi = *(const ushort*)(tB + (((tL + 1) * 128 + d * 2) ^ ((((tL + 1) >> 3) & 7) << 4)));
                w[p] = lo | (hi << 16);
            }
            uint4 o; o.x = w[0]; o.y = w[1]; o.z = w[2]; o.w = w[3];
            *(uint4*)(obase + tA) = o;
        }
    }

    // kv_loc accumulation
    const int c = tid >> 4;
    const int dg = (tid & 15) << 2;
    float a0 = 0.f, a1 = 0.f, a2 = 0.f, a3 = 0.f;
    for (int t = 0; t < L_; ++t) {
        const float kev = ke_s[t][c];
        uint2 rv = *(const uint2*)(tB + ((t * 128 + dg * 2) ^ (((t >> 3) & 7) << 4)));
        float v0, v1, v2, v3;
        unpack2(rv.x, v0, v1); unpack2(rv.y, v2, v3);
        a0 += kev * v0; a1 += kev * v1; a2 += kev * v2; a3 += kev * v3;
    }
    {   // two-level ke column sums
        const int cc = tid & 15, g = tid >> 4;
        float s = 0.f;
        #pragma unroll
        for (int u = 0; u < 8; ++u) s += ke_s[g * 8 + u][cc];
        gsum[cc][g] = s;
    }
    __syncthreads();
    if (tid < C_) {
        float s = 0.f;
        #pragma unroll
        for (int g = 0; g < 16; ++g) s += gsum[tid][g];
        ke_loc[(size_t)bid * C_ + tid] = s;
    }
    *(float4*)(kv_loc + (size_t)bid * 1024 + c * HD_ + dg) = make_float4(a0, a1, a2, a3);
}

// ---------------------------------------------------------------------------
// MFMA intra: per (b,h,chunk):
//   exclusive chunk-prefix of ke_loc/kv_loc computed in-kernel (sum ch<chunk)
//   P^T = Ke·Qn^T (16x16x32, K zero-padded), causal mask, P -> swizzled LDS bf16
//   O = Qn·S0 + P·V  (V from pre-transposed vT)
__global__ __launch_bounds__(256)
void intra_kernel(const ushort* __restrict__ qkcv, const ushort* __restrict__ vT,
                  const float* __restrict__ ke_loc, const float* __restrict__ kv_loc,
                  ushort* __restrict__ xob) {
    const int bid = blockIdx.x;
    const int chunk = bid & (NC_ - 1);
    const int bh = bid >> 4;
    const int b = bh >> 4, h = bh & 15;
    const int t0 = chunk * L_;
    const int tid = threadIdx.x;
    const int wave = tid >> 6, lane = tid & 63;
    const int l15 = lane & 15, lhi = lane >> 4;

    __shared__ __align__(16) ushort ke_bf[128 * 32];
    __shared__ __align__(16) ushort qn_bf[128 * 32];
    __shared__ __align__(16) ushort Vt_s[64 * 128];
    __shared__ __align__(16) ushort Pl[128 * 128];
    __shared__ __align__(16) ushort S0t[64 * 32];
    __shared__ float kesum_s[128][16];
    __shared__ float gsum[16][16];
    __shared__ float e0s[16];

    char* keB = (char*)ke_bf;
    char* qnB = (char*)qn_bf;
    char* vtB = (char*)Vt_s;
    char* plB = (char*)Pl;
    char* s0B = (char*)S0t;

    // ---- stage ke = exp(kc) as bf16 (+ zero pad) ----
    {
        const int t = tid >> 1, c0 = (tid & 1) * 8;
        uint4 raw = *(const uint4*)(qkcv + (size_t)(b * T_ + t0 + t) * NW_ + 256 + h * C_ + c0);
        float f[8]; unpack8(raw, f);
        uint4 o;
        o.x = pack2(__expf(f[0]), __expf(f[1]));
        o.y = pack2(__expf(f[2]), __expf(f[3]));
        o.z = pack2(__expf(f[4]), __expf(f[5]));
        o.w = pack2(__expf(f[6]), __expf(f[7]));
        const int swz = ((t >> 1) & 3) << 4;
        *(uint4*)(keB + ((t * 64 + c0 * 2) ^ swz)) = o;
        *(uint4*)(keB + ((t * 64 + 32 + c0 * 2) ^ swz)) = make_uint4(0, 0, 0, 0);
    }
    // ---- stage Vt (bf16 [d][s] swizzled) from vT global ----
    {
        const int d = tid >> 2, q = tid & 3;
        const ushort* src = vT + ((size_t)bh * 64 + d) * 2048 + t0 + q * 32;
        const int swz = (d & 15) << 4;
        #pragma unroll
        for (int i = 0; i < 4; ++i) {
            uint4 raw = *(const uint4*)(src + i * 8);
            *(uint4*)(vtB + ((d * 256 + q * 64 + i * 16) ^ swz)) = raw;
        }
    }
    // ---- exclusive chunk-prefix: S0t = sum_{ch<chunk} kv_loc (bf16, padded) ----
    {
        const int c = tid >> 4;
        const int d0 = (tid & 15) * 4;
        const float* base = kv_loc + (size_t)(bh * NC_) * 1024 + c * 64 + d0;
        float s0 = 0.f, s1 = 0.f, s2 = 0.f, s3 = 0.f;
        for (int ch = 0; ch < chunk; ++ch) {
            float4 t4 = *(const float4*)(base + ch * 1024);
            s0 += t4.x; s1 += t4.y; s2 += t4.z; s3 += t4.w;
        }
        const float sp[4] = {s0, s1, s2, s3};
        #pragma unroll
        for (int j = 0; j < 4; ++j) {
            const int d = d0 + j;
            const int swz2 = ((d >> 1) & 3) << 4;
            *(ushort*)(s0B + ((d * 64 + c * 2) ^ swz2)) = f2b(sp[j]);
        }
        const int dz = tid >> 2;
        const int off = 32 + (tid & 3) * 8;
        const int swzz = ((dz >> 1) & 3) << 4;
        *(uint2*)(s0B + ((dz * 64 + off) ^ swzz)) = make_uint2(0, 0);
    }
    if (tid < 16) {
        float s = 0.f;
        for (int ch = 0; ch < chunk; ++ch)
            s += ke_loc[(size_t)(bh * NC_ + ch) * C_ + tid];
        e0s[tid] = s;
    }
    __syncthreads();

    // ---- two-level inclusive prefix of ke over t (+ e0) -> kesum_s ----
    {
        const int cc = tid & 15, g = tid >> 4;
        float s = 0.f;
        #pragma unroll
        for (int u = 0; u < 8; ++u) {
            const int t = g * 8 + u;
            s += b2f(*(const ushort*)(keB + ((t * 64 + cc * 2) ^ (((t >> 1) & 3) << 4))));
        }
        gsum[cc][g] = s;
    }
    __syncthreads();
    if (tid < 16) {
        float run = e0s[tid];
        #pragma unroll
        for (int g = 0; g < 16; ++g) { float tmp = gsum[tid][g]; gsum[tid][g] = run; run += tmp; }
    }
    __syncthreads();
    {
        const int cc = tid & 15, g = tid >> 4;
        float run = gsum[cc][g];
        #pragma unroll
        for (int u = 0; u < 8; ++u) {
            const int t = g * 8 + u;
            run += b2f(*(const ushort*)(keB + ((t * 64 + cc * 2) ^ (((t >> 1) & 3) << 4))));
            kesum_s[t][cc] = run;
        }
    }
    __syncthreads();

    // ---- qn = softmax(qc)*scale/(kesum+eps), bf16 (+ zero pad) ----
    if (tid < 128) {
        const int t = tid;
        const ushort* qrow = qkcv + (size_t)(b * T_ + t0 + t) * NW_ + h * C_;
        float qv[16];
        uint4 r0 = *(const uint4*)qrow, r1 = *(const uint4*)(qrow + 8);
        unpack8(r0, qv); unpack8(r1, qv + 8);
        float m = qv[0];
        #pragma unroll
        for (int c = 1; c < 16; ++c) m = fmaxf(m, qv[c]);
        float sum = 0.f;
        #pragma unroll
        for (int c = 0; c < 16; ++c) { qv[c] = __expf(qv[c] - m); sum += qv[c]; }
        const float inv = SCALE_ / sum;
        #pragma unroll
        for (int c = 0; c < 16; ++c) qv[c] = qv[c] * inv / (kesum_s[t][c] + 1e-9f);
        uint4 o0, o1;
        o0.x = pack2(qv[0], qv[1]);   o0.y = pack2(qv[2], qv[3]);
        o0.z = pack2(qv[4], qv[5]);   o0.w = pack2(qv[6], qv[7]);
        o1.x = pack2(qv[8], qv[9]);   o1.y = pack2(qv[10], qv[11]);
        o1.z = pack2(qv[12], qv[13]); o1.w = pack2(qv[14], qv[15]);
        const int swz = ((t >> 1) & 3) << 4;
        *(uint4*)(qnB + ((t * 64) ^ swz)) = o0;
        *(uint4*)(qnB + ((t * 64 + 16) ^ swz)) = o1;
        *(uint4*)(qnB + ((t * 64 + 32) ^ swz)) = make_uint4(0, 0, 0, 0);
        *(uint4*)(qnB + ((t * 64 + 48) ^ swz)) = make_uint4(0, 0, 0, 0);
    }
    __syncthreads();

    // ---- QK: P^T = Ke·Qn^T per 16x16 tile, mask, write Pl (bf16 swizzled) ----
    #pragma unroll
    for (int sr = 0; sr < 2; ++sr) {
        const int sb = wave * 2 + sr;
        const int s_row = sb * 16 + l15;
        short8 af = *(const short8*)(keB + ((s_row * 64 + lhi * 16) ^ (((s_row >> 1) & 3) << 4)));
        #pragma unroll
        for (int tb = 0; tb < 8; ++tb) {
            f32x4 p = (f32x4){0.f, 0.f, 0.f, 0.f};
            if (tb >= sb) {
                const int t_col = tb * 16 + l15;
                short8 bf = *(const short8*)(qnB + ((t_col * 64 + lhi * 16) ^ (((t_col >> 1) & 3) << 4)));
                p = __builtin_amdgcn_mfma_f32_16x16x32_bf16(af, bf, p, 0, 0, 0);
                if (tb == sb) {
                    #pragma unroll
                    for (int j = 0; j < 4; ++j)
                        p[j] = (lhi * 4 + j > l15) ? 0.f : p[j];
                }
            }
            const int t_g = tb * 16 + l15;
            const int sbase = sb * 16 + lhi * 4;
            const int swz = (t_g & 15) << 4;
            *(uint32_t*)(plB + ((t_g * 256 + sbase * 2) ^ swz)) = pack2(p[0], p[1]);
            *(uint32_t*)(plB + ((t_g * 256 + sbase * 2 + 4) ^ swz)) = pack2(p[2], p[3]);
        }
    }
    __syncthreads();

    // ---- O = Qn·S0 + P·V ----
    f32x4 acc[2][4];
    #pragma unroll
    for (int tt = 0; tt < 2; ++tt)
        #pragma unroll
        for (int dt = 0; dt < 4; ++dt) acc[tt][dt] = (f32x4){0.f, 0.f, 0.f, 0.f};

    const int trow = wave * 32;
    #pragma unroll
    for (int tt = 0; tt < 2; ++tt) {
        const int t_g = trow + tt * 16 + l15;
        short8 aq = *(const short8*)(qnB + ((t_g * 64 + lhi * 16) ^ (((t_g >> 1) & 3) << 4)));
        #pragma unroll
        for (int dt = 0; dt < 4; ++dt) {
            const int d = dt * 16 + l15;
            short8 bs = *(const short8*)(s0B + ((d * 64 + lhi * 16) ^ (((d >> 1) & 3) << 4)));
            acc[tt][dt] = __builtin_amdgcn_mfma_f32_16x16x32_bf16(aq, bs, acc[tt][dt], 0, 0, 0);
        }
        const int pswz = (t_g & 15) << 4;
        #pragma unroll
        for (int kb = 0; kb < 4; ++kb) {
            short8 ap = *(const short8*)(plB + ((t_g * 256 + kb * 64 + lhi * 16) ^ pswz));
            #pragma unroll
            for (int dt = 0; dt < 4; ++dt) {
                const int d = dt * 16 + l15;
                short8 bv = *(const short8*)(vtB + ((d * 256 + kb * 64 + lhi * 16) ^ ((d & 15) << 4)));
                acc[tt][dt] = __builtin_amdgcn_mfma_f32_16x16x32_bf16(ap, bv, acc[tt][dt], 0, 0, 0);
            }
        }
    }

    // ---- epilogue ----
    #pragma unroll
    for (int tt = 0; tt < 2; ++tt) {
        const int tg0 = t0 + trow + tt * 16 + lhi * 4;
        #pragma unroll
        for (int dt = 0; dt < 4; ++dt) {
            const int d = dt * 16 + l15;
            ushort* orow = xob + (size_t)(b * T_ + tg0) * D_ + h * HD_ + d;
            #pragma unroll
            for (int j = 0; j < 4; ++j)
                orow[(size_t)j * D_] = f2b(acc[tt][dt][j]);
        }
    }
}

// ---------------------------------------------------------------------------
extern "C" void kernel_launch(void* const* d_in, const int* in_sizes, int n_in,
                              void* d_out, int out_size, void* d_ws, size_t ws_size,
                              hipStream_t stream) {
    const float* x     = (const float*)d_in[0];   // (2,2048,1024)
    const float* w_qkv = (const float*)d_in[1];   // (3072,1024)
    const float* w_out = (const float*)d_in[2];   // (1024,1024)
    const float* code  = (const float*)d_in[3];   // (1,16,16,64)
    float* out = (float*)d_out;                   // (2,2048,1024)

    ushort* xb    = (ushort*)d_ws;                    // 4096*1024
    ushort* WallB = xb + (size_t)4096 * 1024;         // 1536*1024
    ushort* WoB   = WallB + (size_t)1536 * 1024;      // 1024*1024
    ushort* qkcv  = WoB + (size_t)1024 * 1024;        // 4096*1536
    ushort* xob   = qkcv + (size_t)4096 * 1536;       // 4096*1024
    ushort* vT    = xob + (size_t)4096 * 1024;        // 32*64*2048
    float*  ke_loc = (float*)(vT + (size_t)32 * 64 * 2048);  // 512*16
    float*  kv_loc = ke_loc + 512 * 16;               // 512*1024

    // merged casts + weight folding (one launch)
    prep_inputs_kernel<<<3584, 256, 0, stream>>>(x, w_qkv, w_out, code, xb, WallB, WoB);

    // fused qc|kc|v projection: (4096 x 1536 x 1024), bf16 out
    gemm_bf16_kernel<1><<<dim3(12, 32), 256, 0, stream>>>(xb, WallB, qkcv, 4096, NW_, 1024);

    // fused v-transpose + chunk-local sums (locals only; prefix in intra)
    prep_attn_kernel<<<512, 256, 0, stream>>>(qkcv, vT, ke_loc, kv_loc);
    intra_kernel<<<512, 256, 0, stream>>>(qkcv, vT, ke_loc, kv_loc, xob);

    // out = xo @ w_out^T  (4096 x 1024 x 1024), fp32 out
    gemm_bf16_kernel<0><<<dim3(8, 32), 256, 0, stream>>>(xob, WoB, out, 4096, 1024, 1024);
}

// Round 6
// 84.719 us; speedup vs baseline: 7.1524x; 1.0702x over previous
//
#include <hip/hip_runtime.h>
#include <math.h>

// Problem constants (B=2, T=2048, D=1024, H=16, HD=64, C=16)
#define B_    2
#define T_    2048
#define D_    1024
#define H_    16
#define HD_   64
#define C_    16
#define SCALE_ 0.125f      // HEAD_DIM^-0.5
#define L_    128          // time-chunk length
#define NC_   16           // T_/L_
#define QKP_  512          // qkcv row pitch: [qc(256) | kc(256)]

typedef __attribute__((ext_vector_type(8))) short short8;
typedef __attribute__((ext_vector_type(4))) float f32x4;

__device__ inline float b2f(uint32_t u16) {
    return __uint_as_float(u16 << 16);
}
__device__ inline ushort f2b(float f) {   // RNE
    uint32_t u = __float_as_uint(f);
    return (ushort)((u + 0x7FFFu + ((u >> 16) & 1u)) >> 16);
}
__device__ inline uint32_t pack2(float a, float b) {
    return (uint32_t)f2b(a) | ((uint32_t)f2b(b) << 16);
}
__device__ inline void unpack2(uint32_t w, float& a, float& b) {
    a = b2f(w & 0xffffu); b = __uint_as_float(w & 0xffff0000u);
}
__device__ inline void unpack8(uint4 raw, float* dst) {
    unpack2(raw.x, dst[0], dst[1]);
    unpack2(raw.y, dst[2], dst[3]);
    unpack2(raw.z, dst[4], dst[5]);
    unpack2(raw.w, dst[6], dst[7]);
}
__device__ __forceinline__ void gll16(const ushort* g, ushort* l) {
    __builtin_amdgcn_global_load_lds(
        (const __attribute__((address_space(1))) void*)g,
        (__attribute__((address_space(3))) void*)l, 16, 0, 0);
}

// ---------------------------------------------------------------------------
// Merged input prep: blockIdx ranges
//   [0,2048)    : cast x fp32 -> bf16
//   [2048,3072) : cast Wv / w_out -> bf16
//   [3072,3584) : fold fc_code into q/k slices -> WallB rows 0..511
__global__ __launch_bounds__(256)
void prep_inputs_kernel(const float* __restrict__ x, const float* __restrict__ w_qkv,
                        const float* __restrict__ w_out, const float* __restrict__ code,
                        ushort* __restrict__ xb, ushort* __restrict__ WallB,
                        ushort* __restrict__ WoB) {
    const int bid = blockIdx.x;
    if (bid < 3072) {
        const float* in;
        ushort* out;
        int i;
        if (bid < 2048) {
            in = x; out = xb;
            i = bid * 2048 + threadIdx.x * 8;
        } else {
            const int sub = bid - 2048;
            const int isW = sub >> 9;
            in = isW ? w_out : (w_qkv + (size_t)2048 * 1024);
            out = isW ? WoB : (WallB + (size_t)512 * 1024);
            i = (sub & 511) * 2048 + threadIdx.x * 8;
        }
        float4 a = *(const float4*)(in + i);
        float4 b = *(const float4*)(in + i + 4);
        uint4 o;
        o.x = pack2(a.x, a.y); o.y = pack2(a.z, a.w);
        o.z = pack2(b.x, b.y); o.w = pack2(b.z, b.w);
        *(uint4*)(out + i) = o;
    } else {
        const int sub = bid - 3072;      // 0..511
        const int isK = sub >> 8;
        const int row = sub & 255;       // h*16+c
        const int h = row >> 4;
        __shared__ float cs[HD_];
        if (threadIdx.x < HD_) cs[threadIdx.x] = code[row * HD_ + threadIdx.x];
        __syncthreads();
        const float* wbase = w_qkv + (size_t)(isK * D_ + h * HD_) * D_;
        ushort* outp = WallB + (size_t)(isK * 256 + row) * D_;
        for (int e = threadIdx.x; e < D_; e += 256) {
            float acc = 0.f;
            #pragma unroll 8
            for (int d = 0; d < HD_; ++d) acc += wbase[(size_t)d * D_ + e] * cs[d];
            outp[e] = f2b(acc * SCALE_);
        }
    }
}

// ---------------------------------------------------------------------------
// bf16 MFMA GEMM: C[M,N] = A[M,K] @ B[N,K]^T.
// Tile 128x64 (BM x BN), BK=64, 4 waves (wave-tile 32x64, acc 2x4).
// LDS 48KB dbuf -> 3 blocks/CU; grids (768/512 blocks) fully co-resident so
// barrier drains hide under other blocks' MFMA (the 2-phase TLP mechanism).
// MODE 0: fp32 C (pitch N). MODE 1: bf16 C (pitch N).
// MODE 2: gemm1 fused output: cols<512 -> qkcv bf16 (pitch 512);
//         cols>=512 are v -> written TRANSPOSED to vT[bh][d][t].
template<int MODE>
__global__ __launch_bounds__(256)
void gemm_bf16_kernel(const ushort* __restrict__ A, const ushort* __restrict__ Bw,
                      void* __restrict__ Cv, ushort* __restrict__ vTout,
                      int M, int N, int K) {
    __shared__ ushort As[2][128 * 64];   // 2 x 16 KB
    __shared__ ushort Bs[2][64 * 64];    // 2 x 8 KB
    const int tid  = threadIdx.x;
    const int wave = tid >> 6;
    const int lane = tid & 63;

    // XCD swizzle: contiguous tile chunk per XCD (bijective: nwg % 8 == 0)
    const int gx = gridDim.x;
    int f = blockIdx.y * gx + blockIdx.x;
    const int nwg = gx * gridDim.y;
    if ((nwg & 7) == 0) f = (f & 7) * (nwg >> 3) + (f >> 3);
    const int row0 = (f / gx) * 128;
    const int col0 = (f % gx) * 64;

    f32x4 acc[2][4];
    #pragma unroll
    for (int m = 0; m < 2; ++m)
        #pragma unroll
        for (int n = 0; n < 4; ++n) acc[m][n] = (f32x4){0.f, 0.f, 0.f, 0.f};

    // staging constants: linear LDS dest, pre-swizzled global source
    const int srow = lane >> 3;
    const int kA   = ((lane & 7) ^ srow) << 3;
    // fragment-read constants
    const int lane15 = lane & 15;
    const int lhi    = lane >> 4;
    const int axor   = (lane15 & 7) << 4;

    const int NT = K >> 6;

    // stage: 24 segs total (A:16, B:8), 6 per wave
    auto STAGE = [&](int buf, int kk) {
        #pragma unroll
        for (int i = 0; i < 6; ++i) {
            const int sg = wave * 6 + i;
            if (sg < 16) {
                const int r = sg * 8 + srow;
                gll16(A + (size_t)(row0 + r) * K + kk + kA, &As[buf][sg * 512]);
            } else {
                const int sb = sg - 16;
                const int r = sb * 8 + srow;
                gll16(Bw + (size_t)(col0 + r) * K + kk + kA, &Bs[buf][sb * 512]);
            }
        }
    };

    STAGE(0, 0);
    __syncthreads();

    for (int it = 0; it < NT; ++it) {
        const int cur = it & 1;
        if (it + 1 < NT) STAGE(cur ^ 1, (it + 1) << 6);
        const char* Ab = (const char*)As[cur];
        const char* Bb = (const char*)Bs[cur];
        #pragma unroll
        for (int s = 0; s < 2; ++s) {
            short8 af[2], bf[4];
            #pragma unroll
            for (int m = 0; m < 2; ++m) {
                const int r = wave * 32 + m * 16 + lane15;
                const int off = (r * 128 + s * 64 + lhi * 16) ^ axor;
                af[m] = *(const short8*)(Ab + off);
            }
            #pragma unroll
            for (int n = 0; n < 4; ++n) {
                const int r = n * 16 + lane15;
                const int off = (r * 128 + s * 64 + lhi * 16) ^ axor;
                bf[n] = *(const short8*)(Bb + off);
            }
            #pragma unroll
            for (int m = 0; m < 2; ++m)
                #pragma unroll
                for (int n = 0; n < 4; ++n)
                    acc[m][n] = __builtin_amdgcn_mfma_f32_16x16x32_bf16(
                        af[m], bf[n], acc[m][n], 0, 0, 0);
        }
        __syncthreads();   // drains prefetch (vmcnt 0) + protects buffers
    }

    // epilogue: C/D map col=lane&15, row=(lane>>4)*4+j
    #pragma unroll
    for (int m = 0; m < 2; ++m) {
        #pragma unroll
        for (int n = 0; n < 4; ++n) {
            const int row = row0 + wave * 32 + m * 16 + lhi * 4;
            const int col = col0 + n * 16 + lane15;
            if (MODE == 0) {
                float* C = (float*)Cv;
                #pragma unroll
                for (int j = 0; j < 4; ++j)
                    C[(size_t)(row + j) * N + col] = acc[m][n][j];
            } else if (MODE == 1) {
                ushort* C = (ushort*)Cv;
                #pragma unroll
                for (int j = 0; j < 4; ++j)
                    C[(size_t)(row + j) * N + col] = f2b(acc[m][n][j]);
            } else {   // MODE 2
                if (col0 < 512) {
                    ushort* C = (ushort*)Cv;
                    #pragma unroll
                    for (int j = 0; j < 4; ++j)
                        C[(size_t)(row + j) * QKP_ + col] = f2b(acc[m][n][j]);
                } else {
                    const int dg = col - 512;
                    const int h = dg >> 6, d = dg & 63;
                    const int b = row >> 11;
                    const int t = row & 2047;
                    ushort* p = vTout + ((size_t)((b * 16 + h) * 64 + d)) * 2048 + t;
                    *(uint2*)p = make_uint2(pack2(acc[m][n][0], acc[m][n][1]),
                                            pack2(acc[m][n][2], acc[m][n][3]));
                }
            }
        }
    }
}

// ---------------------------------------------------------------------------
// Chunk-local sums (no transpose — vT comes from the GEMM epilogue).
// Per (b,h,chunk): ke_loc[c] = sum_t exp(kc[t,c]);
//                  kv_loc[c,d] = sum_t exp(kc[t,c]) * v[t,d]   (v read from vT)
__global__ __launch_bounds__(256)
void prep_attn_kernel(const ushort* __restrict__ qkcv, const ushort* __restrict__ vT,
                      float* __restrict__ ke_loc, float* __restrict__ kv_loc) {
    const int bid = blockIdx.x;            // bh*NC_ + chunk
    const int chunk = bid & (NC_ - 1);
    const int bh = bid >> 4;
    const int b = bh >> 4, h = bh & 15;
    const int t0 = chunk * L_;
    const int tid = threadIdx.x;
    __shared__ float ke_s[L_][C_];         // 8 KB
    __shared__ float gsum[C_][16];

    // stage ke = exp(kc), fp32
    {
        const int t = tid >> 1, c0 = (tid & 1) * 8;
        uint4 raw = *(const uint4*)(qkcv + (size_t)(b * T_ + t0 + t) * QKP_ + 256 + h * C_ + c0);
        float f[8]; unpack8(raw, f);
        #pragma unroll
        for (int j = 0; j < 8; ++j) ke_s[t][c0 + j] = __expf(f[j]);
    }
    __syncthreads();

    // kv: thread owns (d = tid&63, wave's 4 c's); streams its vT row
    const int d = tid & 63;
    const int cw = tid >> 6;               // wave index = c-quad
    const ushort* vrow = vT + ((size_t)(bh * 64 + d)) * 2048 + t0;
    float a0 = 0.f, a1 = 0.f, a2 = 0.f, a3 = 0.f;
    for (int kb = 0; kb < 16; ++kb) {
        uint4 raw = *(const uint4*)(vrow + kb * 8);
        float v8[8]; unpack8(raw, v8);
        #pragma unroll
        for (int u = 0; u < 8; ++u) {
            const int t = kb * 8 + u;
            a0 += ke_s[t][cw * 4 + 0] * v8[u];
            a1 += ke_s[t][cw * 4 + 1] * v8[u];
            a2 += ke_s[t][cw * 4 + 2] * v8[u];
            a3 += ke_s[t][cw * 4 + 3] * v8[u];
        }
    }
    float* kvb = kv_loc + (size_t)bid * 1024 + d;
    kvb[(cw * 4 + 0) * 64] = a0;
    kvb[(cw * 4 + 1) * 64] = a1;
    kvb[(cw * 4 + 2) * 64] = a2;
    kvb[(cw * 4 + 3) * 64] = a3;

    {   // two-level ke column sums -> ke_loc
        const int cc = tid & 15, g = tid >> 4;
        float s = 0.f;
        #pragma unroll
        for (int u = 0; u < 8; ++u) s += ke_s[g * 8 + u][cc];
        gsum[cc][g] = s;
    }
    __syncthreads();
    if (tid < C_) {
        float s = 0.f;
        #pragma unroll
        for (int g = 0; g < 16; ++g) s += gsum[tid][g];
        ke_loc[(size_t)bid * C_ + tid] = s;
    }
}

// ---------------------------------------------------------------------------
// MFMA intra: per (b,h,chunk):
//   exclusive chunk-prefix of ke_loc/kv_loc computed in-kernel (sum ch<chunk)
//   P^T = Ke·Qn^T (16x16x32, K zero-padded), causal mask, P -> swizzled LDS bf16
//   O = Qn·S0 + P·V  (V from GEMM-produced vT)
__global__ __launch_bounds__(256)
void intra_kernel(const ushort* __restrict__ qkcv, const ushort* __restrict__ vT,
                  const float* __restrict__ ke_loc, const float* __restrict__ kv_loc,
                  ushort* __restrict__ xob) {
    const int bid = blockIdx.x;
    const int chunk = bid & (NC_ - 1);
    const int bh = bid >> 4;
    const int b = bh >> 4, h = bh & 15;
    const int t0 = chunk * L_;
    const int tid = threadIdx.x;
    const int wave = tid >> 6, lane = tid & 63;
    const int l15 = lane & 15, lhi = lane >> 4;

    __shared__ __align__(16) ushort ke_bf[128 * 32];
    __shared__ __align__(16) ushort qn_bf[128 * 32];
    __shared__ __align__(16) ushort Vt_s[64 * 128];
    __shared__ __align__(16) ushort Pl[128 * 128];
    __shared__ __align__(16) ushort S0t[64 * 32];
    __shared__ float kesum_s[128][16];
    __shared__ float gsum[16][16];
    __shared__ float e0s[16];

    char* keB = (char*)ke_bf;
    char* qnB = (char*)qn_bf;
    char* vtB = (char*)Vt_s;
    char* plB = (char*)Pl;
    char* s0B = (char*)S0t;

    // ---- stage ke = exp(kc) as bf16 (+ zero pad) ----
    {
        const int t = tid >> 1, c0 = (tid & 1) * 8;
        uint4 raw = *(const uint4*)(qkcv + (size_t)(b * T_ + t0 + t) * QKP_ + 256 + h * C_ + c0);
        float f[8]; unpack8(raw, f);
        uint4 o;
        o.x = pack2(__expf(f[0]), __expf(f[1]));
        o.y = pack2(__expf(f[2]), __expf(f[3]));
        o.z = pack2(__expf(f[4]), __expf(f[5]));
        o.w = pack2(__expf(f[6]), __expf(f[7]));
        const int swz = ((t >> 1) & 3) << 4;
        *(uint4*)(keB + ((t * 64 + c0 * 2) ^ swz)) = o;
        *(uint4*)(keB + ((t * 64 + 32 + c0 * 2) ^ swz)) = make_uint4(0, 0, 0, 0);
    }
    // ---- stage Vt (bf16 [d][s] swizzled) from vT global ----
    {
        const int d = tid >> 2, q = tid & 3;
        const ushort* src = vT + ((size_t)bh * 64 + d) * 2048 + t0 + q * 32;
        const int swz = (d & 15) << 4;
        #pragma unroll
        for (int i = 0; i < 4; ++i) {
            uint4 raw = *(const uint4*)(src + i * 8);
            *(uint4*)(vtB + ((d * 256 + q * 64 + i * 16) ^ swz)) = raw;
        }
    }
    // ---- exclusive chunk-prefix: S0t = sum_{ch<chunk} kv_loc (bf16, padded) ----
    {
        const int c = tid >> 4;
        const int d0 = (tid & 15) * 4;
        const float* base = kv_loc + (size_t)(bh * NC_) * 1024 + c * 64 + d0;
        float s0 = 0.f, s1 = 0.f, s2 = 0.f, s3 = 0.f;
        for (int ch = 0; ch < chunk; ++ch) {
            float4 t4 = *(const float4*)(base + ch * 1024);
            s0 += t4.x; s1 += t4.y; s2 += t4.z; s3 += t4.w;
        }
        const float sp[4] = {s0, s1, s2, s3};
        #pragma unroll
        for (int j = 0; j < 4; ++j) {
            const int d = d0 + j;
            const int swz2 = ((d >> 1) & 3) << 4;
            *(ushort*)(s0B + ((d * 64 + c * 2) ^ swz2)) = f2b(sp[j]);
        }
        const int dz = tid >> 2;
        const int off = 32 + (tid & 3) * 8;
        const int swzz = ((dz >> 1) & 3) << 4;
        *(uint2*)(s0B + ((dz * 64 + off) ^ swzz)) = make_uint2(0, 0);
    }
    if (tid < 16) {
        float s = 0.f;
        for (int ch = 0; ch < chunk; ++ch)
            s += ke_loc[(size_t)(bh * NC_ + ch) * C_ + tid];
        e0s[tid] = s;
    }
    __syncthreads();

    // ---- two-level inclusive prefix of ke over t (+ e0) -> kesum_s ----
    {
        const int cc = tid & 15, g = tid >> 4;
        float s = 0.f;
        #pragma unroll
        for (int u = 0; u < 8; ++u) {
            const int t = g * 8 + u;
            s += b2f(*(const ushort*)(keB + ((t * 64 + cc * 2) ^ (((t >> 1) & 3) << 4))));
        }
        gsum[cc][g] = s;
    }
    __syncthreads();
    if (tid < 16) {
        float run = e0s[tid];
        #pragma unroll
        for (int g = 0; g < 16; ++g) { float tmp = gsum[tid][g]; gsum[tid][g] = run; run += tmp; }
    }
    __syncthreads();
    {
        const int cc = tid & 15, g = tid >> 4;
        float run = gsum[cc][g];
        #pragma unroll
        for (int u = 0; u < 8; ++u) {
            const int t = g * 8 + u;
            run += b2f(*(const ushort*)(keB + ((t * 64 + cc * 2) ^ (((t >> 1) & 3) << 4))));
            kesum_s[t][cc] = run;
        }
    }
    __syncthreads();

    // ---- qn = softmax(qc)*scale/(kesum+eps), bf16 (+ zero pad) ----
    if (tid < 128) {
        const int t = tid;
        const ushort* qrow = qkcv + (size_t)(b * T_ + t0 + t) * QKP_ + h * C_;
        float qv[16];
        uint4 r0 = *(const uint4*)qrow, r1 = *(const uint4*)(qrow + 8);
        unpack8(r0, qv); unpack8(r1, qv + 8);
        float m = qv[0];
        #pragma unroll
        for (int c = 1; c < 16; ++c) m = fmaxf(m, qv[c]);
        float sum = 0.f;
        #pragma unroll
        for (int c = 0; c < 16; ++c) { qv[c] = __expf(qv[c] - m); sum += qv[c]; }
        const float inv = SCALE_ / sum;
        #pragma unroll
        for (int c = 0; c < 16; ++c) qv[c] = qv[c] * inv / (kesum_s[t][c] + 1e-9f);
        uint4 o0, o1;
        o0.x = pack2(qv[0], qv[1]);   o0.y = pack2(qv[2], qv[3]);
        o0.z = pack2(qv[4], qv[5]);   o0.w = pack2(qv[6], qv[7]);
        o1.x = pack2(qv[8], qv[9]);   o1.y = pack2(qv[10], qv[11]);
        o1.z = pack2(qv[12], qv[13]); o1.w = pack2(qv[14], qv[15]);
        const int swz = ((t >> 1) & 3) << 4;
        *(uint4*)(qnB + ((t * 64) ^ swz)) = o0;
        *(uint4*)(qnB + ((t * 64 + 16) ^ swz)) = o1;
        *(uint4*)(qnB + ((t * 64 + 32) ^ swz)) = make_uint4(0, 0, 0, 0);
        *(uint4*)(qnB + ((t * 64 + 48) ^ swz)) = make_uint4(0, 0, 0, 0);
    }
    __syncthreads();

    // ---- QK: P^T = Ke·Qn^T per 16x16 tile, mask, write Pl (bf16 swizzled) ----
    #pragma unroll
    for (int sr = 0; sr < 2; ++sr) {
        const int sb = wave * 2 + sr;
        const int s_row = sb * 16 + l15;
        short8 af = *(const short8*)(keB + ((s_row * 64 + lhi * 16) ^ (((s_row >> 1) & 3) << 4)));
        #pragma unroll
        for (int tb = 0; tb < 8; ++tb) {
            f32x4 p = (f32x4){0.f, 0.f, 0.f, 0.f};
            if (tb >= sb) {
                const int t_col = tb * 16 + l15;
                short8 bf = *(const short8*)(qnB + ((t_col * 64 + lhi * 16) ^ (((t_col >> 1) & 3) << 4)));
                p = __builtin_amdgcn_mfma_f32_16x16x32_bf16(af, bf, p, 0, 0, 0);
                if (tb == sb) {
                    #pragma unroll
                    for (int j = 0; j < 4; ++j)
                        p[j] = (lhi * 4 + j > l15) ? 0.f : p[j];
                }
            }
            const int t_g = tb * 16 + l15;
            const int sbase = sb * 16 + lhi * 4;
            const int swz = (t_g & 15) << 4;
            *(uint32_t*)(plB + ((t_g * 256 + sbase * 2) ^ swz)) = pack2(p[0], p[1]);
            *(uint32_t*)(plB + ((t_g * 256 + sbase * 2 + 4) ^ swz)) = pack2(p[2], p[3]);
        }
    }
    __syncthreads();

    // ---- O = Qn·S0 + P·V ----
    f32x4 acc[2][4];
    #pragma unroll
    for (int tt = 0; tt < 2; ++tt)
        #pragma unroll
        for (int dt = 0; dt < 4; ++dt) acc[tt][dt] = (f32x4){0.f, 0.f, 0.f, 0.f};

    const int trow = wave * 32;
    #pragma unroll
    for (int tt = 0; tt < 2; ++tt) {
        const int t_g = trow + tt * 16 + l15;
        short8 aq = *(const short8*)(qnB + ((t_g * 64 + lhi * 16) ^ (((t_g >> 1) & 3) << 4)));
        #pragma unroll
        for (int dt = 0; dt < 4; ++dt) {
            const int d = dt * 16 + l15;
            short8 bs = *(const short8*)(s0B + ((d * 64 + lhi * 16) ^ (((d >> 1) & 3) << 4)));
            acc[tt][dt] = __builtin_amdgcn_mfma_f32_16x16x32_bf16(aq, bs, acc[tt][dt], 0, 0, 0);
        }
        const int pswz = (t_g & 15) << 4;
        #pragma unroll
        for (int kb = 0; kb < 4; ++kb) {
            short8 ap = *(const short8*)(plB + ((t_g * 256 + kb * 64 + lhi * 16) ^ pswz));
            #pragma unroll
            for (int dt = 0; dt < 4; ++dt) {
                const int d = dt * 16 + l15;
                short8 bv = *(const short8*)(vtB + ((d * 256 + kb * 64 + lhi * 16) ^ ((d & 15) << 4)));
                acc[tt][dt] = __builtin_amdgcn_mfma_f32_16x16x32_bf16(ap, bv, acc[tt][dt], 0, 0, 0);
            }
        }
    }

    // ---- epilogue ----
    #pragma unroll
    for (int tt = 0; tt < 2; ++tt) {
        const int tg0 = t0 + trow + tt * 16 + lhi * 4;
        #pragma unroll
        for (int dt = 0; dt < 4; ++dt) {
            const int d = dt * 16 + l15;
            ushort* orow = xob + (size_t)(b * T_ + tg0) * D_ + h * HD_ + d;
            #pragma unroll
            for (int j = 0; j < 4; ++j)
                orow[(size_t)j * D_] = f2b(acc[tt][dt][j]);
        }
    }
}

// ---------------------------------------------------------------------------
extern "C" void kernel_launch(void* const* d_in, const int* in_sizes, int n_in,
                              void* d_out, int out_size, void* d_ws, size_t ws_size,
                              hipStream_t stream) {
    const float* x     = (const float*)d_in[0];   // (2,2048,1024)
    const float* w_qkv = (const float*)d_in[1];   // (3072,1024)
    const float* w_out = (const float*)d_in[2];   // (1024,1024)
    const float* code  = (const float*)d_in[3];   // (1,16,16,64)
    float* out = (float*)d_out;                   // (2,2048,1024)

    ushort* xb    = (ushort*)d_ws;                    // 4096*1024
    ushort* WallB = xb + (size_t)4096 * 1024;         // 1536*1024
    ushort* WoB   = WallB + (size_t)1536 * 1024;      // 1024*1024
    ushort* qkcv  = WoB + (size_t)1024 * 1024;        // 4096*512 (qc|kc)
    ushort* xob   = qkcv + (size_t)4096 * 512;        // 4096*1024
    ushort* vT    = xob + (size_t)4096 * 1024;        // 32*64*2048
    float*  ke_loc = (float*)(vT + (size_t)32 * 64 * 2048);  // 512*16
    float*  kv_loc = ke_loc + 512 * 16;               // 512*1024

    // merged casts + weight folding (one launch)
    prep_inputs_kernel<<<3584, 256, 0, stream>>>(x, w_qkv, w_out, code, xb, WallB, WoB);

    // fused qc|kc|v projection: (4096 x 1536 x 1024); qc/kc -> qkcv, v -> vT (transposed)
    gemm_bf16_kernel<2><<<dim3(24, 32), 256, 0, stream>>>(xb, WallB, qkcv, vT, 4096, 1536, 1024);

    // chunk-local sums (locals only; prefix in intra)
    prep_attn_kernel<<<512, 256, 0, stream>>>(qkcv, vT, ke_loc, kv_loc);
    intra_kernel<<<512, 256, 0, stream>>>(qkcv, vT, ke_loc, kv_loc, xob);

    // out = xo @ w_out^T  (4096 x 1024 x 1024), fp32 out
    gemm_bf16_kernel<0><<<dim3(16, 32), 256, 0, stream>>>(xob, WoB, out, nullptr, 4096, 1024, 1024);
}

// Round 7
// 79.738 us; speedup vs baseline: 7.5991x; 1.0625x over previous
//
#include <hip/hip_runtime.h>
#include <math.h>

// Problem constants (B=2, T=2048, D=1024, H=16, HD=64, C=16)
#define B_    2
#define T_    2048
#define D_    1024
#define H_    16
#define HD_   64
#define C_    16
#define SCALE_ 0.125f      // HEAD_DIM^-0.5
#define L_    128          // time-chunk length
#define NC_   16           // T_/L_
#define QKP_  512          // qkcv row pitch: [qc(256) | kc(256)]

typedef __attribute__((ext_vector_type(8))) short short8;
typedef __attribute__((ext_vector_type(4))) float f32x4;

__device__ inline float b2f(uint32_t u16) {
    return __uint_as_float(u16 << 16);
}
__device__ inline ushort f2b(float f) {   // RNE
    uint32_t u = __float_as_uint(f);
    return (ushort)((u + 0x7FFFu + ((u >> 16) & 1u)) >> 16);
}
__device__ inline uint32_t pack2(float a, float b) {
    return (uint32_t)f2b(a) | ((uint32_t)f2b(b) << 16);
}
__device__ inline void unpack2(uint32_t w, float& a, float& b) {
    a = b2f(w & 0xffffu); b = __uint_as_float(w & 0xffff0000u);
}
__device__ inline void unpack8(uint4 raw, float* dst) {
    unpack2(raw.x, dst[0], dst[1]);
    unpack2(raw.y, dst[2], dst[3]);
    unpack2(raw.z, dst[4], dst[5]);
    unpack2(raw.w, dst[6], dst[7]);
}
__device__ __forceinline__ void gll16(const ushort* g, ushort* l) {
    __builtin_amdgcn_global_load_lds(
        (const __attribute__((address_space(1))) void*)g,
        (__attribute__((address_space(3))) void*)l, 16, 0, 0);
}

// ---------------------------------------------------------------------------
// Merged input prep: blockIdx ranges
//   [0,2048)    : cast x fp32 -> bf16
//   [2048,3072) : cast Wv / w_out -> bf16
//   [3072,3200) : fold fc_code into q/k slices -> WallB rows 0..511
//                 128 blocks = (isK, h, e-quarter); each computes ALL 16 c's
//                 from ONE pass over the 64x256 weight slice (16x less traffic
//                 than the old per-(isK,row) decomposition).
__global__ __launch_bounds__(256)
void prep_inputs_kernel(const float* __restrict__ x, const float* __restrict__ w_qkv,
                        const float* __restrict__ w_out, const float* __restrict__ code,
                        ushort* __restrict__ xb, ushort* __restrict__ WallB,
                        ushort* __restrict__ WoB) {
    const int bid = blockIdx.x;
    if (bid < 3072) {
        const float* in;
        ushort* out;
        int i;
        if (bid < 2048) {
            in = x; out = xb;
            i = bid * 2048 + threadIdx.x * 8;
        } else {
            const int sub = bid - 2048;
            const int isW = sub >> 9;
            in = isW ? w_out : (w_qkv + (size_t)2048 * 1024);
            out = isW ? WoB : (WallB + (size_t)512 * 1024);
            i = (sub & 511) * 2048 + threadIdx.x * 8;
        }
        float4 a = *(const float4*)(in + i);
        float4 b = *(const float4*)(in + i + 4);
        uint4 o;
        o.x = pack2(a.x, a.y); o.y = pack2(a.z, a.w);
        o.z = pack2(b.x, b.y); o.w = pack2(b.z, b.w);
        *(uint4*)(out + i) = o;
    } else {
        const int sub = bid - 3072;      // 0..127
        const int isK = sub >> 6;
        const int h   = (sub >> 2) & 15;
        const int eq  = sub & 3;
        const int e   = eq * 256 + threadIdx.x;
        __shared__ __align__(16) float cs[C_][HD_];   // code[h] slice, 4 KB
        {
            float* csf = &cs[0][0];
            *(float4*)(csf + threadIdx.x * 4) =
                *(const float4*)(code + h * 1024 + threadIdx.x * 4);
        }
        __syncthreads();
        const float* wbase = w_qkv + ((size_t)(isK * D_ + h * HD_)) * D_ + e;
        float acc[C_];
        #pragma unroll
        for (int c = 0; c < C_; ++c) acc[c] = 0.f;
        #pragma unroll 4
        for (int db = 0; db < 16; ++db) {
            const float w0 = wbase[(size_t)(db * 4 + 0) * D_];
            const float w1 = wbase[(size_t)(db * 4 + 1) * D_];
            const float w2 = wbase[(size_t)(db * 4 + 2) * D_];
            const float w3 = wbase[(size_t)(db * 4 + 3) * D_];
            #pragma unroll
            for (int c = 0; c < C_; ++c) {
                float4 cv = *(const float4*)&cs[c][db * 4];
                acc[c] += w0 * cv.x; acc[c] += w1 * cv.y;
                acc[c] += w2 * cv.z; acc[c] += w3 * cv.w;
            }
        }
        ushort* outp = WallB + (size_t)(isK * 256 + h * 16) * D_ + e;
        #pragma unroll
        for (int c = 0; c < C_; ++c)
            outp[(size_t)c * D_] = f2b(acc[c] * SCALE_);
    }
}

// ---------------------------------------------------------------------------
// bf16 MFMA GEMM: C[M,N] = A[M,K] @ B[N,K]^T.
// Tile 128x64 (BM x BN), BK=64, 4 waves (wave-tile 32x64, acc 2x4).
// LDS 48KB dbuf -> 3 blocks/CU; grids (768/512 blocks) fully co-resident so
// barrier drains hide under other blocks' MFMA (the 2-phase TLP mechanism).
// MODE 0: fp32 C (pitch N). MODE 1: bf16 C (pitch N).
// MODE 2: gemm1 fused output: cols<512 -> qkcv bf16 (pitch 512);
//         cols>=512 are v -> written TRANSPOSED to vT[bh][d][t].
template<int MODE>
__global__ __launch_bounds__(256)
void gemm_bf16_kernel(const ushort* __restrict__ A, const ushort* __restrict__ Bw,
                      void* __restrict__ Cv, ushort* __restrict__ vTout,
                      int M, int N, int K) {
    __shared__ ushort As[2][128 * 64];   // 2 x 16 KB
    __shared__ ushort Bs[2][64 * 64];    // 2 x 8 KB
    const int tid  = threadIdx.x;
    const int wave = tid >> 6;
    const int lane = tid & 63;

    // XCD swizzle: contiguous tile chunk per XCD (bijective: nwg % 8 == 0)
    const int gx = gridDim.x;
    int f = blockIdx.y * gx + blockIdx.x;
    const int nwg = gx * gridDim.y;
    if ((nwg & 7) == 0) f = (f & 7) * (nwg >> 3) + (f >> 3);
    const int row0 = (f / gx) * 128;
    const int col0 = (f % gx) * 64;

    f32x4 acc[2][4];
    #pragma unroll
    for (int m = 0; m < 2; ++m)
        #pragma unroll
        for (int n = 0; n < 4; ++n) acc[m][n] = (f32x4){0.f, 0.f, 0.f, 0.f};

    // staging constants: linear LDS dest, pre-swizzled global source
    const int srow = lane >> 3;
    const int kA   = ((lane & 7) ^ srow) << 3;
    // fragment-read constants
    const int lane15 = lane & 15;
    const int lhi    = lane >> 4;
    const int axor   = (lane15 & 7) << 4;

    const int NT = K >> 6;

    // stage: 24 segs total (A:16, B:8), 6 per wave
    auto STAGE = [&](int buf, int kk) {
        #pragma unroll
        for (int i = 0; i < 6; ++i) {
            const int sg = wave * 6 + i;
            if (sg < 16) {
                const int r = sg * 8 + srow;
                gll16(A + (size_t)(row0 + r) * K + kk + kA, &As[buf][sg * 512]);
            } else {
                const int sb = sg - 16;
                const int r = sb * 8 + srow;
                gll16(Bw + (size_t)(col0 + r) * K + kk + kA, &Bs[buf][sb * 512]);
            }
        }
    };

    STAGE(0, 0);
    __syncthreads();

    for (int it = 0; it < NT; ++it) {
        const int cur = it & 1;
        if (it + 1 < NT) STAGE(cur ^ 1, (it + 1) << 6);
        const char* Ab = (const char*)As[cur];
        const char* Bb = (const char*)Bs[cur];
        #pragma unroll
        for (int s = 0; s < 2; ++s) {
            short8 af[2], bf[4];
            #pragma unroll
            for (int m = 0; m < 2; ++m) {
                const int r = wave * 32 + m * 16 + lane15;
                const int off = (r * 128 + s * 64 + lhi * 16) ^ axor;
                af[m] = *(const short8*)(Ab + off);
            }
            #pragma unroll
            for (int n = 0; n < 4; ++n) {
                const int r = n * 16 + lane15;
                const int off = (r * 128 + s * 64 + lhi * 16) ^ axor;
                bf[n] = *(const short8*)(Bb + off);
            }
            #pragma unroll
            for (int m = 0; m < 2; ++m)
                #pragma unroll
                for (int n = 0; n < 4; ++n)
                    acc[m][n] = __builtin_amdgcn_mfma_f32_16x16x32_bf16(
                        af[m], bf[n], acc[m][n], 0, 0, 0);
        }
        __syncthreads();   // drains prefetch (vmcnt 0) + protects buffers
    }

    // epilogue: C/D map col=lane&15, row=(lane>>4)*4+j
    #pragma unroll
    for (int m = 0; m < 2; ++m) {
        #pragma unroll
        for (int n = 0; n < 4; ++n) {
            const int row = row0 + wave * 32 + m * 16 + lhi * 4;
            const int col = col0 + n * 16 + lane15;
            if (MODE == 0) {
                float* C = (float*)Cv;
                #pragma unroll
                for (int j = 0; j < 4; ++j)
                    C[(size_t)(row + j) * N + col] = acc[m][n][j];
            } else if (MODE == 1) {
                ushort* C = (ushort*)Cv;
                #pragma unroll
                for (int j = 0; j < 4; ++j)
                    C[(size_t)(row + j) * N + col] = f2b(acc[m][n][j]);
            } else {   // MODE 2
                if (col0 < 512) {
                    ushort* C = (ushort*)Cv;
                    #pragma unroll
                    for (int j = 0; j < 4; ++j)
                        C[(size_t)(row + j) * QKP_ + col] = f2b(acc[m][n][j]);
                } else {
                    const int dg = col - 512;
                    const int h = dg >> 6, d = dg & 63;
                    const int b = row >> 11;
                    const int t = row & 2047;
                    ushort* p = vTout + ((size_t)((b * 16 + h) * 64 + d)) * 2048 + t;
                    *(uint2*)p = make_uint2(pack2(acc[m][n][0], acc[m][n][1]),
                                            pack2(acc[m][n][2], acc[m][n][3]));
                }
            }
        }
    }
}

// ---------------------------------------------------------------------------
// Chunk-local sums. Per (b,h,chunk): ke_loc[c] = sum_t exp(kc[t,c]);
//                  kv_loc[c,d] = sum_t exp(kc[t,c]) * v[t,d]   (v from vT)
__global__ __launch_bounds__(256)
void prep_attn_kernel(const ushort* __restrict__ qkcv, const ushort* __restrict__ vT,
                      float* __restrict__ ke_loc, float* __restrict__ kv_loc) {
    const int bid = blockIdx.x;            // bh*NC_ + chunk
    const int chunk = bid & (NC_ - 1);
    const int bh = bid >> 4;
    const int b = bh >> 4, h = bh & 15;
    const int t0 = chunk * L_;
    const int tid = threadIdx.x;
    __shared__ float ke_s[L_][C_];         // 8 KB
    __shared__ float gsum[C_][16];

    // stage ke = exp(kc), fp32
    {
        const int t = tid >> 1, c0 = (tid & 1) * 8;
        uint4 raw = *(const uint4*)(qkcv + (size_t)(b * T_ + t0 + t) * QKP_ + 256 + h * C_ + c0);
        float f[8]; unpack8(raw, f);
        #pragma unroll
        for (int j = 0; j < 8; ++j) ke_s[t][c0 + j] = __expf(f[j]);
    }
    __syncthreads();

    // kv: thread owns (d = tid&63, wave's 4 c's); streams its vT row
    const int d = tid & 63;
    const int cw = tid >> 6;               // wave index = c-quad
    const ushort* vrow = vT + ((size_t)(bh * 64 + d)) * 2048 + t0;
    float a0 = 0.f, a1 = 0.f, a2 = 0.f, a3 = 0.f;
    for (int kb = 0; kb < 16; ++kb) {
        uint4 raw = *(const uint4*)(vrow + kb * 8);
        float v8[8]; unpack8(raw, v8);
        #pragma unroll
        for (int u = 0; u < 8; ++u) {
            const int t = kb * 8 + u;
            a0 += ke_s[t][cw * 4 + 0] * v8[u];
            a1 += ke_s[t][cw * 4 + 1] * v8[u];
            a2 += ke_s[t][cw * 4 + 2] * v8[u];
            a3 += ke_s[t][cw * 4 + 3] * v8[u];
        }
    }
    float* kvb = kv_loc + (size_t)bid * 1024 + d;
    kvb[(cw * 4 + 0) * 64] = a0;
    kvb[(cw * 4 + 1) * 64] = a1;
    kvb[(cw * 4 + 2) * 64] = a2;
    kvb[(cw * 4 + 3) * 64] = a3;

    {   // two-level ke column sums -> ke_loc
        const int cc = tid & 15, g = tid >> 4;
        float s = 0.f;
        #pragma unroll
        for (int u = 0; u < 8; ++u) s += ke_s[g * 8 + u][cc];
        gsum[cc][g] = s;
    }
    __syncthreads();
    if (tid < C_) {
        float s = 0.f;
        #pragma unroll
        for (int g = 0; g < 16; ++g) s += gsum[tid][g];
        ke_loc[(size_t)bid * C_ + tid] = s;
    }
}

// ---------------------------------------------------------------------------
// MFMA intra, 8 waves (512 threads): per (b,h,chunk):
//   exclusive chunk-prefix of ke_loc/kv_loc computed in-kernel (sum ch<chunk)
//   P^T = Ke·Qn^T (one s-block per wave), causal mask, P -> swizzled LDS bf16
//   O = Qn·S0 + P·V  (one t-tile per wave; V from GEMM-produced vT)
__global__ __launch_bounds__(512)
void intra_kernel(const ushort* __restrict__ qkcv, const ushort* __restrict__ vT,
                  const float* __restrict__ ke_loc, const float* __restrict__ kv_loc,
                  ushort* __restrict__ xob) {
    const int bid = blockIdx.x;
    const int chunk = bid & (NC_ - 1);
    const int bh = bid >> 4;
    const int b = bh >> 4, h = bh & 15;
    const int t0 = chunk * L_;
    const int tid = threadIdx.x;
    const int wave = tid >> 6, lane = tid & 63;
    const int l15 = lane & 15, lhi = lane >> 4;

    __shared__ __align__(16) ushort ke_bf[128 * 32];
    __shared__ __align__(16) ushort qn_bf[128 * 32];
    __shared__ __align__(16) ushort Vt_s[64 * 128];
    __shared__ __align__(16) ushort Pl[128 * 128];
    __shared__ __align__(16) ushort S0t[64 * 32];
    __shared__ float kesum_s[128][16];
    __shared__ float gsum[16][16];
    __shared__ float e0s[16];

    char* keB = (char*)ke_bf;
    char* qnB = (char*)qn_bf;
    char* vtB = (char*)Vt_s;
    char* plB = (char*)Pl;
    char* s0B = (char*)S0t;

    // ---- stage ke = exp(kc) as bf16 (+ zero pad) ----
    if (tid < 256) {
        const int t = tid >> 1, c0 = (tid & 1) * 8;
        uint4 raw = *(const uint4*)(qkcv + (size_t)(b * T_ + t0 + t) * QKP_ + 256 + h * C_ + c0);
        float f[8]; unpack8(raw, f);
        uint4 o;
        o.x = pack2(__expf(f[0]), __expf(f[1]));
        o.y = pack2(__expf(f[2]), __expf(f[3]));
        o.z = pack2(__expf(f[4]), __expf(f[5]));
        o.w = pack2(__expf(f[6]), __expf(f[7]));
        const int swz = ((t >> 1) & 3) << 4;
        *(uint4*)(keB + ((t * 64 + c0 * 2) ^ swz)) = o;
        *(uint4*)(keB + ((t * 64 + 32 + c0 * 2) ^ swz)) = make_uint4(0, 0, 0, 0);
    }
    // ---- stage Vt (bf16 [d][s] swizzled) from vT global, all 512 threads ----
    {
        const int d = tid >> 3, qq = tid & 7;
        const ushort* src = vT + ((size_t)bh * 64 + d) * 2048 + t0 + qq * 16;
        const int swz = (d & 15) << 4;
        #pragma unroll
        for (int ii = 0; ii < 2; ++ii) {
            uint4 raw = *(const uint4*)(src + ii * 8);
            *(uint4*)(vtB + ((d * 256 + qq * 32 + ii * 16) ^ swz)) = raw;
        }
    }
    // ---- exclusive chunk-prefix: S0t = sum_{ch<chunk} kv_loc (bf16, padded) ----
    if (tid < 256) {
        const int c = tid >> 4;
        const int d0 = (tid & 15) * 4;
        const float* base = kv_loc + (size_t)(bh * NC_) * 1024 + c * 64 + d0;
        float s0 = 0.f, s1 = 0.f, s2 = 0.f, s3 = 0.f;
        for (int ch = 0; ch < chunk; ++ch) {
            float4 t4 = *(const float4*)(base + ch * 1024);
            s0 += t4.x; s1 += t4.y; s2 += t4.z; s3 += t4.w;
        }
        const float sp[4] = {s0, s1, s2, s3};
        #pragma unroll
        for (int j = 0; j < 4; ++j) {
            const int d = d0 + j;
            const int swz2 = ((d >> 1) & 3) << 4;
            *(ushort*)(s0B + ((d * 64 + c * 2) ^ swz2)) = f2b(sp[j]);
        }
        const int dz = tid >> 2;
        const int off = 32 + (tid & 3) * 8;
        const int swzz = ((dz >> 1) & 3) << 4;
        *(uint2*)(s0B + ((dz * 64 + off) ^ swzz)) = make_uint2(0, 0);
    }
    if (tid < 16) {
        float s = 0.f;
        for (int ch = 0; ch < chunk; ++ch)
            s += ke_loc[(size_t)(bh * NC_ + ch) * C_ + tid];
        e0s[tid] = s;
    }
    __syncthreads();

    // ---- two-level inclusive prefix of ke over t (+ e0) -> kesum_s ----
    if (tid < 256) {
        const int cc = tid & 15, g = tid >> 4;
        float s = 0.f;
        #pragma unroll
        for (int u = 0; u < 8; ++u) {
            const int t = g * 8 + u;
            s += b2f(*(const ushort*)(keB + ((t * 64 + cc * 2) ^ (((t >> 1) & 3) << 4))));
        }
        gsum[cc][g] = s;
    }
    __syncthreads();
    if (tid < 16) {
        float run = e0s[tid];
        #pragma unroll
        for (int g = 0; g < 16; ++g) { float tmp = gsum[tid][g]; gsum[tid][g] = run; run += tmp; }
    }
    __syncthreads();
    if (tid < 256) {
        const int cc = tid & 15, g = tid >> 4;
        float run = gsum[cc][g];
        #pragma unroll
        for (int u = 0; u < 8; ++u) {
            const int t = g * 8 + u;
            run += b2f(*(const ushort*)(keB + ((t * 64 + cc * 2) ^ (((t >> 1) & 3) << 4))));
            kesum_s[t][cc] = run;
        }
    }
    __syncthreads();

    // ---- qn = softmax(qc)*scale/(kesum+eps), bf16 (+ zero pad) ----
    if (tid < 128) {
        const int t = tid;
        const ushort* qrow = qkcv + (size_t)(b * T_ + t0 + t) * QKP_ + h * C_;
        float qv[16];
        uint4 r0 = *(const uint4*)qrow, r1 = *(const uint4*)(qrow + 8);
        unpack8(r0, qv); unpack8(r1, qv + 8);
        float m = qv[0];
        #pragma unroll
        for (int c = 1; c < 16; ++c) m = fmaxf(m, qv[c]);
        float sum = 0.f;
        #pragma unroll
        for (int c = 0; c < 16; ++c) { qv[c] = __expf(qv[c] - m); sum += qv[c]; }
        const float inv = SCALE_ / sum;
        #pragma unroll
        for (int c = 0; c < 16; ++c) qv[c] = qv[c] * inv / (kesum_s[t][c] + 1e-9f);
        uint4 o0, o1;
        o0.x = pack2(qv[0], qv[1]);   o0.y = pack2(qv[2], qv[3]);
        o0.z = pack2(qv[4], qv[5]);   o0.w = pack2(qv[6], qv[7]);
        o1.x = pack2(qv[8], qv[9]);   o1.y = pack2(qv[10], qv[11]);
        o1.z = pack2(qv[12], qv[13]); o1.w = pack2(qv[14], qv[15]);
        const int swz = ((t >> 1) & 3) << 4;
        *(uint4*)(qnB + ((t * 64) ^ swz)) = o0;
        *(uint4*)(qnB + ((t * 64 + 16) ^ swz)) = o1;
        *(uint4*)(qnB + ((t * 64 + 32) ^ swz)) = make_uint4(0, 0, 0, 0);
        *(uint4*)(qnB + ((t * 64 + 48) ^ swz)) = make_uint4(0, 0, 0, 0);
    }
    __syncthreads();

    // ---- QK: one s-block per wave: P^T = Ke·Qn^T, mask, write Pl ----
    {
        const int sb = wave;               // 0..7
        const int s_row = sb * 16 + l15;
        short8 af = *(const short8*)(keB + ((s_row * 64 + lhi * 16) ^ (((s_row >> 1) & 3) << 4)));
        #pragma unroll
        for (int tb = 0; tb < 8; ++tb) {
            f32x4 p = (f32x4){0.f, 0.f, 0.f, 0.f};
            if (tb >= sb) {
                const int t_col = tb * 16 + l15;
                short8 bf = *(const short8*)(qnB + ((t_col * 64 + lhi * 16) ^ (((t_col >> 1) & 3) << 4)));
                p = __builtin_amdgcn_mfma_f32_16x16x32_bf16(af, bf, p, 0, 0, 0);
                if (tb == sb) {
                    #pragma unroll
                    for (int j = 0; j < 4; ++j)
                        p[j] = (lhi * 4 + j > l15) ? 0.f : p[j];
                }
            }
            const int t_g = tb * 16 + l15;
            const int sbase = sb * 16 + lhi * 4;
            const int swz = (t_g & 15) << 4;
            *(uint32_t*)(plB + ((t_g * 256 + sbase * 2) ^ swz)) = pack2(p[0], p[1]);
            *(uint32_t*)(plB + ((t_g * 256 + sbase * 2 + 4) ^ swz)) = pack2(p[2], p[3]);
        }
    }
    __syncthreads();

    // ---- O = Qn·S0 + P·V : one t-tile per wave ----
    f32x4 acc4[4];
    #pragma unroll
    for (int dt = 0; dt < 4; ++dt) acc4[dt] = (f32x4){0.f, 0.f, 0.f, 0.f};

    {
        const int t_g = wave * 16 + l15;
        short8 aq = *(const short8*)(qnB + ((t_g * 64 + lhi * 16) ^ (((t_g >> 1) & 3) << 4)));
        #pragma unroll
        for (int dt = 0; dt < 4; ++dt) {
            const int d = dt * 16 + l15;
            short8 bs = *(const short8*)(s0B + ((d * 64 + lhi * 16) ^ (((d >> 1) & 3) << 4)));
            acc4[dt] = __builtin_amdgcn_mfma_f32_16x16x32_bf16(aq, bs, acc4[dt], 0, 0, 0);
        }
        const int pswz = (t_g & 15) << 4;
        #pragma unroll
        for (int kb = 0; kb < 4; ++kb) {
            short8 ap = *(const short8*)(plB + ((t_g * 256 + kb * 64 + lhi * 16) ^ pswz));
            #pragma unroll
            for (int dt = 0; dt < 4; ++dt) {
                const int d = dt * 16 + l15;
                short8 bv = *(const short8*)(vtB + ((d * 256 + kb * 64 + lhi * 16) ^ ((d & 15) << 4)));
                acc4[dt] = __builtin_amdgcn_mfma_f32_16x16x32_bf16(ap, bv, acc4[dt], 0, 0, 0);
            }
        }
    }

    // ---- epilogue ----
    {
        const int tg0 = t0 + wave * 16 + lhi * 4;
        #pragma unroll
        for (int dt = 0; dt < 4; ++dt) {
            const int d = dt * 16 + l15;
            ushort* orow = xob + (size_t)(b * T_ + tg0) * D_ + h * HD_ + d;
            #pragma unroll
            for (int j = 0; j < 4; ++j)
                orow[(size_t)j * D_] = f2b(acc4[dt][j]);
        }
    }
}

// ---------------------------------------------------------------------------
extern "C" void kernel_launch(void* const* d_in, const int* in_sizes, int n_in,
                              void* d_out, int out_size, void* d_ws, size_t ws_size,
                              hipStream_t stream) {
    const float* x     = (const float*)d_in[0];   // (2,2048,1024)
    const float* w_qkv = (const float*)d_in[1];   // (3072,1024)
    const float* w_out = (const float*)d_in[2];   // (1024,1024)
    const float* code  = (const float*)d_in[3];   // (1,16,16,64)
    float* out = (float*)d_out;                   // (2,2048,1024)

    ushort* xb    = (ushort*)d_ws;                    // 4096*1024
    ushort* WallB = xb + (size_t)4096 * 1024;         // 1536*1024
    ushort* WoB   = WallB + (size_t)1536 * 1024;      // 1024*1024
    ushort* qkcv  = WoB + (size_t)1024 * 1024;        // 4096*512 (qc|kc)
    ushort* xob   = qkcv + (size_t)4096 * 512;        // 4096*1024
    ushort* vT    = xob + (size_t)4096 * 1024;        // 32*64*2048
    float*  ke_loc = (float*)(vT + (size_t)32 * 64 * 2048);  // 512*16
    float*  kv_loc = ke_loc + 512 * 16;               // 512*1024

    // merged casts + weight folding (one launch)
    prep_inputs_kernel<<<3200, 256, 0, stream>>>(x, w_qkv, w_out, code, xb, WallB, WoB);

    // fused qc|kc|v projection: (4096 x 1536 x 1024); qc/kc -> qkcv, v -> vT (transposed)
    gemm_bf16_kernel<2><<<dim3(24, 32), 256, 0, stream>>>(xb, WallB, qkcv, vT, 4096, 1536, 1024);

    // chunk-local sums (locals only; prefix in intra)
    prep_attn_kernel<<<512, 256, 0, stream>>>(qkcv, vT, ke_loc, kv_loc);
    intra_kernel<<<512, 512, 0, stream>>>(qkcv, vT, ke_loc, kv_loc, xob);

    // out = xo @ w_out^T  (4096 x 1024 x 1024), fp32 out
    gemm_bf16_kernel<0><<<dim3(16, 32), 256, 0, stream>>>(xob, WoB, out, nullptr, 4096, 1024, 1024);
}